// Round 8
// baseline (4997.700 us; speedup 1.0000x reference)
//
#include <hip/hip_runtime.h>

#define NN 8192
#define NE 131072
#define KNN 20
#define SPL 8            // kNN column splits (x-dim => XCD pinning)
#define CPS (NN/SPL)     // 1024 cols per split
#define GT_RPB 64        // gramtopk rows per block

typedef __attribute__((ext_vector_type(4))) float f32x4;
typedef __attribute__((ext_vector_type(8))) __bf16 bf16x8;

// ---------------- utility ----------------
__global__ void k_zero(float* p, int n){
  int i = blockIdx.x*256 + threadIdx.x;
  if (i < n) p[i] = 0.f;
}
__global__ void k_zero_i(int* p, int n){
  int i = blockIdx.x*256 + threadIdx.x;
  if (i < n) p[i] = 0;
}

__device__ __forceinline__ unsigned short f2bf(float x){
  unsigned u = __float_as_uint(x);
  unsigned r = (u + 0x7fff + ((u >> 16) & 1)) >> 16;
  return (unsigned short)r;
}
__device__ __forceinline__ float bf2f(unsigned short h){
  return __uint_as_float((unsigned)h << 16);
}

// ---------------- graph prep ----------------
__global__ void k_count(const int* __restrict__ src, const int* __restrict__ dst,
                        int* cs, int* cd){
  int e = blockIdx.x*256 + threadIdx.x;
  if (e < NE){ atomicAdd(&cs[src[e]], 1); atomicAdd(&cd[dst[e]], 1); }
}
__global__ void k_deg(const int* cs, const int* cd, float* dout, float* din){
  int i = blockIdx.x*256 + threadIdx.x;
  if (i < NN){
    dout[i] = rsqrtf((float)max(cs[i], 1));
    din[i]  = rsqrtf((float)max(cd[i], 1));
  }
}
__global__ void k_scan(const int* __restrict__ cnt, int* __restrict__ off){
  __shared__ int sh[256];
  __shared__ int carry;
  int tid = threadIdx.x;
  if (tid == 0) carry = 0;
  __syncthreads();
  for (int base = 0; base < NN; base += 256){
    int v = cnt[base + tid];
    int x = v;
    sh[tid] = x; __syncthreads();
    for (int o = 1; o < 256; o <<= 1){
      int y = (tid >= o) ? sh[tid - o] : 0;
      __syncthreads();
      x += y; sh[tid] = x;
      __syncthreads();
    }
    off[base + tid] = carry + x - v;
    __syncthreads();
    if (tid == 255){
      carry += x;
      if (base + 256 == NN) off[NN] = carry;
    }
    __syncthreads();
  }
}
__global__ void k_fill(const int* __restrict__ src, const int* __restrict__ dst,
                       const int* __restrict__ roff, int* cursor, int* csr){
  int e = blockIdx.x*256 + threadIdx.x;
  if (e < NE){
    int d = dst[e];
    int p = atomicAdd(&cursor[d], 1);
    csr[roff[d] + p] = src[e];
  }
}

// ---------------- gconv1 fused (3 -> 256) ----------------
__global__ void k_gconv1(const float* __restrict__ feat, const int* __restrict__ roff,
                         const int* __restrict__ csr, const float* __restrict__ dout,
                         const float* __restrict__ din, const float* __restrict__ Wc1,
                         const float* __restrict__ bc1, float* __restrict__ h1){
  int wid = threadIdx.x >> 6, lane = threadIdx.x & 63;
  int i = blockIdx.x*4 + wid;
  float a0=0.f, a1=0.f, a2=0.f;
  int beg = roff[i], end = roff[i+1];
  for (int t = beg + lane; t < end; t += 64){
    int s = csr[t]; float w = dout[s];
    a0 += feat[s*3+0]*w; a1 += feat[s*3+1]*w; a2 += feat[s*3+2]*w;
  }
  for (int m = 32; m; m >>= 1){
    a0 += __shfl_xor(a0, m); a1 += __shfl_xor(a1, m); a2 += __shfl_xor(a2, m);
  }
  float dn = din[i];
  a0 *= dn; a1 *= dn; a2 *= dn;
  for (int c = lane; c < 256; c += 64){
    float r = a0*Wc1[c] + a1*Wc1[256+c] + a2*Wc1[512+c] + bc1[c];
    h1[(size_t)i*256 + c] = fmaxf(r, 0.f);
  }
}

// ---------------- row squared norms (C=256) ----------------
__global__ void k_sq(const float* __restrict__ X, float* __restrict__ sq){
  int wid = threadIdx.x >> 6, lane = threadIdx.x & 63;
  int i = blockIdx.x*4 + wid;
  float4 v = *(const float4*)&X[(size_t)i*256 + lane*4];
  float s = v.x*v.x + v.y*v.y + v.z*v.z + v.w*v.w;
  for (int m = 32; m; m >>= 1) s += __shfl_xor(s, m);
  if (lane == 0) sq[i] = s;
}

// ---------------- split f32 -> [hi|lo] bf16, Xcat[n][512] ----------------
__global__ void k_split(const float* __restrict__ X, unsigned short* __restrict__ xcat){
  int row = blockIdx.x, c = threadIdx.x;
  float x = X[(size_t)row*256 + c];
  unsigned short h = f2bf(x);
  unsigned short lo = f2bf(x - bf2f(h));
  xcat[(size_t)row*512 + c] = h;
  xcat[(size_t)row*512 + 256 + c] = lo;
}

// ---------------- FUSED gram + top-K partial selection (v4) ----------------
// R7 post-mortem: the bottleneck was NEVER the scan — it was the per-step
// gload_lds + vmcnt(0)-drain + 2x barrier structure at 2 blocks/CU (~12.8k cy
// wall-clock per staging step, 96 steps/block). v4 removes LDS staging from
// the K-loop entirely: A and B fragments are loaded global->VGPR directly
// (L2-hot; B-split pinned per XCD, A tiny), letting the compiler pipeline
// loads against MFMAs with per-wave vmcnt. Barriers: 2 per ct (key-tile
// handoff) = 16 per block, vs 208 before. 64 rows/block halves B L2 traffic.
// Block: 64 rows x one 1024-col split; wave = 32x64 sub-tile (2mf x 4nf).
// Exactness: lane owns (row, 32-col quarter), 256 candidates -> private
// sorted top-20 (any true row-top-20 elem has <=19 subset elems smaller, so it
// survives); 4-lane pop-merge -> sorted 20-list per (row,split); ties resolved
// by (val,idx) in merges; in-lane strict-< is stable (ascending col order).
__global__ __launch_bounds__(256)
void k_gramtopk(const unsigned short* __restrict__ Xcat, const float* __restrict__ sq,
                float* __restrict__ pd, int* __restrict__ pi){
  __shared__ float tile[GT_RPB][132];   // 33.8 KB keys
  __shared__ float sqr[GT_RPB];
  __shared__ float sqc[128];

  int tid = threadIdx.x;
  int lw = tid >> 6, l = tid & 63;
  int split = blockIdx.x;          // x fastest => bid%8 = split => XCD pinning
  int rb = blockIdx.y*GT_RPB;
  int cb0 = split*CPS;

  if (tid < GT_RPB) sqr[tid] = sq[rb + tid];

  // wave tile geometry: 4 waves = 2(m) x 2(n), each 32 rows x 64 cols
  int wm = lw >> 1, wn = lw & 1;
  int fm = l & 15, kg = l >> 4;

  // global fragment base pointers (in shorts); imm offsets cover k within row
  const unsigned short* aptr0 = Xcat + (size_t)(rb + wm*32 +  0 + fm)*512 + kg*8;
  const unsigned short* aptr1 = Xcat + (size_t)(rb + wm*32 + 16 + fm)*512 + kg*8;
  const unsigned short* bptr[4];
  #pragma unroll
  for (int nf = 0; nf < 4; nf++)
    bptr[nf] = Xcat + (size_t)(cb0 + wn*64 + nf*16 + fm)*512 + kg*8;

  // per-lane topk state: lane owns (row = tid>>2, quarter q = tid&3 -> 32 cols)
  int myrow = tid >> 2, q = tid & 3;
  float kd[KNN]; int ki[KNN];
  #pragma unroll
  for (int u = 0; u < KNN; u++){ kd[u] = INFINITY; ki[u] = 0x7fffffff; }

  #pragma unroll 1
  for (int ct = 0; ct < CPS/128; ct++){
    if (tid < 128) sqc[tid] = sq[cb0 + ct*128 + tid];

    f32x4 acc[2][4];
    #pragma unroll
    for (int m = 0; m < 2; m++)
      #pragma unroll
      for (int n = 0; n < 4; n++) acc[m][n] = (f32x4){0.f,0.f,0.f,0.f};

    // K-loop: 24 mfma-K-steps of 32; sections A{hi,lo,hi} x B{hi,hi,lo}.
    // No barriers, no LDS: pure load->MFMA, compiler-pipelined.
    #pragma unroll 2
    for (int t = 0; t < 24; t++){
      int sec = t >> 3;
      int k0 = (t & 7)*32;
      int ka = ((sec == 1) ? 256 : 0) + k0;   // shorts
      int kb = ((sec == 2) ? 256 : 0) + k0;
      bf16x8 a0 = *(const bf16x8*)(aptr0 + ka);
      bf16x8 a1 = *(const bf16x8*)(aptr1 + ka);
      #pragma unroll
      for (int nf = 0; nf < 4; nf++){
        bf16x8 b = *(const bf16x8*)(bptr[nf] + kb);
        acc[0][nf] = __builtin_amdgcn_mfma_f32_16x16x32_bf16(a0, b, acc[0][nf], 0, 0, 0);
        acc[1][nf] = __builtin_amdgcn_mfma_f32_16x16x32_bf16(a1, b, acc[1][nf], 0, 0, 0);
      }
    }
    #pragma unroll
    for (int nf = 0; nf < 4; nf++) bptr[nf] += 128*512;   // next 128 B-rows

    __syncthreads();   // previous ct's scan done before tile overwrite

    // keys into tile. C/D: col = lane&15, row = (lane>>4)*4 + reg
    #pragma unroll
    for (int mf = 0; mf < 2; mf++){
      #pragma unroll
      for (int nf = 0; nf < 4; nf++){
        int ocol = wn*64 + nf*16 + fm;
        float sc = sqc[ocol];
        #pragma unroll
        for (int r = 0; r < 4; r++){
          int orow = wm*32 + mf*16 + kg*4 + r;
          tile[orow][ocol] = (sqr[orow] + sc) - 2.f*acc[mf][nf][r];
        }
      }
    }
    __syncthreads();

    // scan own (row, quarter): 8 steps x 4 keys, straight-line insertion
#define INSE(kc, jc) { \
      if ((kc) < kd[KNN-1]){ \
        float nk = (kc); int ni = (jc); \
        _Pragma("unroll") \
        for (int u = 0; u < KNN; u++){ \
          bool sw = nk < kd[u]; \
          float tv = kd[u]; int ti = ki[u]; \
          if (sw){ kd[u] = nk; ki[u] = ni; nk = tv; ni = ti; } \
        } \
      } }
    int jb0 = cb0 + ct*128 + q*32;
    #pragma unroll 1
    for (int st = 0; st < 8; st++){
      float4 kv = *(const float4*)&tile[myrow][q*32 + st*4];
      int jb = jb0 + st*4;
      float t19 = kd[KNN-1];
      float mn = fminf(fminf(kv.x, kv.y), fminf(kv.z, kv.w));
      if (__any(mn < t19)){
        INSE(kv.x, jb+0);
        INSE(kv.y, jb+1);
        INSE(kv.z, jb+2);
        INSE(kv.w, jb+3);
      }
    }
#undef INSE
  }

  // 4-lane (quarter-group) merge: pop global min 20x -> sorted list per (row,split)
  size_t base = ((size_t)(rb + myrow)*SPL + split)*20;
  #pragma unroll 1
  for (int r = 0; r < KNN; r++){
    float bv = kd[0]; int bi = ki[0];
    #pragma unroll
    for (int m = 1; m <= 2; m <<= 1){
      float ov = __shfl_xor(bv, m); int oi = __shfl_xor(bi, m);
      if (ov < bv || (ov == bv && oi < bi)){ bv = ov; bi = oi; }
    }
    if (ki[0] == bi){   // winner (col idx unique)
      #pragma unroll
      for (int u = 0; u < KNN-1; u++){ kd[u] = kd[u+1]; ki[u] = ki[u+1]; }
      kd[KNN-1] = INFINITY; ki[KNN-1] = 0x7fffffff;
    }
    if (q == 0){ pd[base + r] = bv; pi[base + r] = bi; }
  }
}

// ---------------- merge 8 sorted 20-lists/row -> exact top-20 ----------------
__global__ __launch_bounds__(256)
void k_knn_merge(const float* __restrict__ pd, const int* __restrict__ pi,
                 int* __restrict__ idxo){
  int tid = threadIdx.x, lw = tid >> 6, l = tid & 63;
  int row = blockIdx.x*4 + lw;
  float v0, v1, v2, v3, v4; int i0, i1, i2, i3, i4;
  if (l < 32){
    size_t base = (size_t)row*(SPL*20) + (l >> 2)*20 + (l & 3)*5;  // sorted chunk
    v0 = pd[base+0]; v1 = pd[base+1]; v2 = pd[base+2]; v3 = pd[base+3]; v4 = pd[base+4];
    i0 = pi[base+0]; i1 = pi[base+1]; i2 = pi[base+2]; i3 = pi[base+3]; i4 = pi[base+4];
  } else {
    v0 = v1 = v2 = v3 = v4 = INFINITY;
    i0 = i1 = i2 = i3 = i4 = 0x7fffffff;
  }
  #pragma unroll 1
  for (int r = 0; r < KNN; r++){
    float bv = v0; int bi = i0;
    #pragma unroll
    for (int mm = 32; mm; mm >>= 1){
      float ov = __shfl_xor(bv, mm); int oi = __shfl_xor(bi, mm);
      if (ov < bv || (ov == bv && oi < bi)){ bv = ov; bi = oi; }
    }
    if (i0 == bi){ v0=v1;i0=i1; v1=v2;i1=i2; v2=v3;i2=i3; v3=v4;i3=i4; v4=INFINITY; i4=0x7fffffff; }
    if (l == 0) idxo[(size_t)row*KNN + r] = bi;
  }
}

// ---------------- Wd = Wtop - Wbot ----------------
__global__ void k_wd(const float* __restrict__ W, float* __restrict__ Wd, int rows, int M){
  int t = blockIdx.x*256 + threadIdx.x;
  if (t < rows*M) Wd[t] = W[t] - W[rows*M + t];
}

// ---------------- generic tiled matmul: C = A(nxK) @ B(KxM) [+bias][relu] ----------------
__global__ __launch_bounds__(256)
void k_mm(const float* __restrict__ A, const float* __restrict__ B,
          const float* __restrict__ bias, float* __restrict__ Cout,
          int n, int Kd, int M, int relu){
  __shared__ float la[16][68], lb[16][68];
  int tid = threadIdx.x;
  int rb = blockIdx.y*64, cb = blockIdx.x*64;
  int lr = tid >> 2, lq = (tid & 3)*4;
  int ty = tid >> 4, tx = tid & 15;
  float acc[4][4] = {};
  for (int k0 = 0; k0 < Kd; k0 += 16){
    __syncthreads();
    #pragma unroll
    for (int u = 0; u < 4; u++){
      int k = k0 + lq + u;
      la[lq+u][lr] = (k < Kd) ? A[(size_t)(rb+lr)*Kd + k] : 0.f;
    }
    int kk = tid >> 4; int cc = (tid & 15)*4;
    #pragma unroll
    for (int u = 0; u < 4; u++){
      int c = cb + cc + u; int k = k0 + kk;
      lb[kk][cc+u] = (k < Kd && c < M) ? B[(size_t)k*M + c] : 0.f;
    }
    __syncthreads();
    #pragma unroll
    for (int k = 0; k < 16; k++){
      float4 a = *(const float4*)&la[k][ty*4];
      float4 b = *(const float4*)&lb[k][tx*4];
      float avv[4] = {a.x,a.y,a.z,a.w}, bvv[4] = {b.x,b.y,b.z,b.w};
      #pragma unroll
      for (int u = 0; u < 4; u++)
        #pragma unroll
        for (int v = 0; v < 4; v++) acc[u][v] += avv[u]*bvv[v];
    }
  }
  #pragma unroll
  for (int u = 0; u < 4; u++){
    int r = rb + ty*4 + u;
    #pragma unroll
    for (int v = 0; v < 4; v++){
      int c = cb + tx*4 + v;
      if (c < M){
        float x = acc[u][v] + (bias ? bias[c] : 0.f);
        if (relu) x = fmaxf(x, 0.f);
        Cout[(size_t)r*M + c] = x;
      }
    }
  }
}

// ---------------- stats over A[i]+P[j] per channel ----------------
template<int C>
__global__ __launch_bounds__(256)
void k_stats1(const float* __restrict__ A, const float* __restrict__ P,
              const int* __restrict__ idx, float* __restrict__ ssum, float* __restrict__ ssq){
  __shared__ int si[128], sj[128];
  int tid = threadIdx.x;
  int s0 = blockIdx.x*128;
  if (tid < 128){ si[tid] = (s0 + tid)/KNN; sj[tid] = idx[s0 + tid]; }
  __syncthreads();
  constexpr int MPAR = 256/C;
  int tc = tid % C, sr = tid / C;
  float s = 0.f, q = 0.f;
  for (int m = sr; m < 128; m += MPAR){
    float v = A[(size_t)si[m]*C + tc] + P[(size_t)sj[m]*C + tc];
    s += v; q += v*v;
  }
  if constexpr (MPAR > 1){
    __shared__ float rs[256], rq[256];
    rs[tid] = s; rq[tid] = q; __syncthreads();
    if (sr == 0){
      for (int u = 1; u < MPAR; u++){ s += rs[u*C + tc]; q += rq[u*C + tc]; }
    }
  }
  if (sr == 0){ atomicAdd(&ssum[tc], s); atomicAdd(&ssq[tc], q); }
}

// ---------------- column stats over dense X (rows = N*KNN) ----------------
template<int C>
__global__ __launch_bounds__(256)
void k_colstats(const float* __restrict__ X, float* __restrict__ ssum, float* __restrict__ ssq){
  constexpr int MPAR = 256/C;
  int tid = threadIdx.x;
  int tc = tid % C, sr = tid / C;
  int base = blockIdx.x*256;
  float s = 0.f, q = 0.f;
  for (int m = sr; m < 256; m += MPAR){
    float v = X[(size_t)(base + m)*C + tc];
    s += v; q += v*v;
  }
  if constexpr (MPAR > 1){
    __shared__ float rs[256], rq[256];
    rs[tid] = s; rq[tid] = q; __syncthreads();
    if (sr == 0){
      for (int u = 1; u < MPAR; u++){ s += rs[u*C + tc]; q += rq[u*C + tc]; }
    }
  }
  if (sr == 0){ atomicAdd(&ssum[tc], s); atomicAdd(&ssq[tc], q); }
}

__global__ void k_bn_final(const float* __restrict__ ssum, const float* __restrict__ ssq,
                           const float* __restrict__ g, const float* __restrict__ be,
                           float* __restrict__ sb, float* __restrict__ tb, int C, float invn){
  int c = threadIdx.x;
  if (c < C){
    float mu = ssum[c]*invn;
    float var = fmaxf(ssq[c]*invn - mu*mu, 0.f);
    float s = g[c]*rsqrtf(var + 1e-5f);
    sb[c] = s; tb[c] = be[c] - mu*s;
  }
}

// ---------------- per-edge matmul: out = relu(bn1(A[i]+P[j])) @ W + bias ----------------
template<int C>
__global__ __launch_bounds__(256)
void k_edge_mm(const float* __restrict__ A, const float* __restrict__ P,
               const int* __restrict__ idx, const float* __restrict__ sb,
               const float* __restrict__ tb, const float* __restrict__ W,
               const float* __restrict__ bias, float* __restrict__ out){
  constexpr int BM   = (C == 256) ? 32 : 64;
  constexpr int KT   = (C == 256) ? 16 : 64;
  constexpr int COLG = C/8;
  constexpr int ROWG = 256/COLG;
  constexpr int EPT  = BM/ROWG;
  constexpr int MPAR = 256/C;
  __shared__ float e2[BM][C+1];
  __shared__ float wt[KT][C+4];
  __shared__ int sj[BM];
  int tid = threadIdx.x;
  int s0 = blockIdx.x*BM;
  if (tid < BM) sj[tid] = idx[s0 + tid];
  __syncthreads();
  for (int mb = 0; mb < BM; mb += MPAR){
    int m = mb + tid / C;
    int c = tid % C;
    int i = (s0 + m)/KNN;
    int j = sj[m];
    float v = (A[(size_t)i*C + c] + P[(size_t)j*C + c])*sb[c] + tb[c];
    e2[m][c] = fmaxf(v, 0.f);
  }
  float acc[EPT][8];
  #pragma unroll
  for (int m = 0; m < EPT; m++)
    #pragma unroll
    for (int u = 0; u < 8; u++) acc[m][u] = 0.f;
  int tr = tid / COLG, tc = tid % COLG;
  for (int kt = 0; kt < C; kt += KT){
    __syncthreads();
    for (int t = tid; t < KT*C; t += 256){
      wt[t / C][t % C] = W[(size_t)(kt + t/C)*C + (t % C)];
    }
    __syncthreads();
    #pragma unroll 4
    for (int k = 0; k < KT; k++){
      float4 w0 = *(const float4*)&wt[k][tc*8];
      float4 w1 = *(const float4*)&wt[k][tc*8 + 4];
      float b[8] = {w0.x,w0.y,w0.z,w0.w,w1.x,w1.y,w1.z,w1.w};
      #pragma unroll
      for (int m = 0; m < EPT; m++){
        float a = e2[tr*EPT + m][kt + k];
        #pragma unroll
        for (int u = 0; u < 8; u++) acc[m][u] += a*b[u];
      }
    }
  }
  #pragma unroll
  for (int m = 0; m < EPT; m++){
    int row = s0 + tr*EPT + m;
    float4 o0, o1;
    o0.x = acc[m][0] + bias[tc*8+0]; o0.y = acc[m][1] + bias[tc*8+1];
    o0.z = acc[m][2] + bias[tc*8+2]; o0.w = acc[m][3] + bias[tc*8+3];
    o1.x = acc[m][4] + bias[tc*8+4]; o1.y = acc[m][5] + bias[tc*8+5];
    o1.z = acc[m][6] + bias[tc*8+6]; o1.w = acc[m][7] + bias[tc*8+7];
    *(float4*)&out[(size_t)row*C + tc*8]     = o0;
    *(float4*)&out[(size_t)row*C + tc*8 + 4] = o1;
  }
}

// ---------------- bn2 + relu + max over K ----------------
template<int C>
__global__ void k_maxpool(const float* __restrict__ X, const float* __restrict__ sb,
                          const float* __restrict__ tb, float* __restrict__ H){
  constexpr int NPB = 256/C;
  int node = blockIdx.x*NPB + threadIdx.x / C;
  int c = threadIdx.x % C;
  float s = sb[c], t = tb[c];
  float mx = 0.f;
  for (int k = 0; k < KNN; k++){
    float v = X[(size_t)(node*KNN + k)*C + c]*s + t;
    mx = fmaxf(mx, v);
  }
  H[(size_t)node*C + c] = mx;
}

// ---------------- gconv aggregation ----------------
template<int C>
__global__ void k_agg(const float* __restrict__ X, const int* __restrict__ roff,
                      const int* __restrict__ csr, const float* __restrict__ dout,
                      const float* __restrict__ din, float* __restrict__ XA){
  int i = blockIdx.x; int c = threadIdx.x;
  float acc = 0.f;
  int b = roff[i], e = roff[i+1];
  for (int t = b; t < e; t++){
    int s = csr[t];
    acc += X[(size_t)s*C + c]*dout[s];
  }
  XA[(size_t)i*C + c] = acc*din[i];
}

// ================= host =================
extern "C" void kernel_launch(void* const* d_in, const int* in_sizes, int n_in,
                              void* d_out, int out_size, void* d_ws, size_t ws_size,
                              hipStream_t stream){
  const float* feat = (const float*)d_in[0];
  const int*   src  = (const int*)d_in[1];
  const int*   dst  = (const int*)d_in[2];
  const float* Wc1  = (const float*)d_in[3];
  const float* bc1  = (const float*)d_in[4];
  const float* Wc2  = (const float*)d_in[5];
  const float* bc2  = (const float*)d_in[6];
  const float* Wc3  = (const float*)d_in[7];
  const float* bc3  = (const float*)d_in[8];
  const float* W11  = (const float*)d_in[9];
  const float* b11  = (const float*)d_in[10];
  const float* g11  = (const float*)d_in[11];
  const float* be11 = (const float*)d_in[12];
  const float* W12  = (const float*)d_in[13];
  const float* b12  = (const float*)d_in[14];
  const float* g12  = (const float*)d_in[15];
  const float* be12 = (const float*)d_in[16];
  const float* W21  = (const float*)d_in[17];
  const float* b21  = (const float*)d_in[18];
  const float* g21  = (const float*)d_in[19];
  const float* be21 = (const float*)d_in[20];
  const float* W22  = (const float*)d_in[21];
  const float* b22  = (const float*)d_in[22];
  const float* g22  = (const float*)d_in[23];
  const float* be22 = (const float*)d_in[24];
  float* out = (float*)d_out;

  char* w = (char*)d_ws; size_t off = 0;
  auto alloc = [&](size_t bytes)->void*{
    void* p = w + off;
    off += bytes; off = (off + 255) & ~(size_t)255;
    return p;
  };
  int* cnt_s  = (int*)alloc(NN*4);
  int* cnt_d  = (int*)alloc(NN*4);
  int* roff   = (int*)alloc((NN+1)*4);
  int* cursor = (int*)alloc(NN*4);
  int* csr    = (int*)alloc(NE*4);
  int* idx    = (int*)alloc((size_t)NN*KNN*4);
  float* dout = (float*)alloc(NN*4);
  float* din  = (float*)alloc(NN*4);
  float* sqv  = (float*)alloc(NN*4);
  float* h1   = (float*)alloc((size_t)NN*256*4);
  float* h2   = (float*)alloc((size_t)NN*256*4);
  float* h3   = (float*)alloc((size_t)NN*256*4);
  float* h4   = (float*)alloc((size_t)NN*64*4);
  float* xa   = (float*)alloc((size_t)NN*256*4);
  float* Abuf = (float*)alloc((size_t)NN*256*4);
  float* Pbuf = (float*)alloc((size_t)NN*256*4);
  float* Wd   = (float*)alloc(256*256*4);
  float* ssum = (float*)alloc(256*4);
  float* ssq  = (float*)alloc(256*4);
  float* sbn  = (float*)alloc(256*4);
  float* tbn  = (float*)alloc(256*4);
  float* out2 = (float*)alloc((size_t)NN*KNN*256*4);   // 167.8 MB
  // kNN scratch aliases out2 (consumed before edge_mm writes out2):
  float* pd = out2;                                           // NN*SPL*20*4 = 5.24 MB
  int*   pi = (int*)(out2 + (size_t)NN*SPL*20);               // 5.24 MB
  unsigned short* xcat = (unsigned short*)((char*)pi + (size_t)NN*SPL*20*4);  // 8.4 MB
  (void)ws_size; (void)n_in; (void)in_sizes; (void)out_size;

  const float invn = 1.0f / (float)(NN*KNN);

  // graph prep
  k_zero_i<<<32, 256, 0, stream>>>(cnt_s, NN);
  k_zero_i<<<32, 256, 0, stream>>>(cnt_d, NN);
  k_zero_i<<<32, 256, 0, stream>>>(cursor, NN);
  k_count<<<NE/256, 256, 0, stream>>>(src, dst, cnt_s, cnt_d);
  k_deg<<<32, 256, 0, stream>>>(cnt_s, cnt_d, dout, din);
  k_scan<<<1, 256, 0, stream>>>(cnt_d, roff);
  k_fill<<<NE/256, 256, 0, stream>>>(src, dst, roff, cursor, csr);

  // gconv1 -> h1
  k_gconv1<<<NN/4, 256, 0, stream>>>(feat, roff, csr, dout, din, Wc1, bc1, h1);

  // ---- edge conv 1 (input h1, 256 -> 256 -> 256) ----
  k_sq<<<NN/4, 256, 0, stream>>>(h1, sqv);
  k_split<<<NN, 256, 0, stream>>>(h1, xcat);
  k_gramtopk<<<dim3(SPL, NN/GT_RPB), 256, 0, stream>>>(xcat, sqv, pd, pi);
  k_knn_merge<<<NN/4, 256, 0, stream>>>(pd, pi, idx);
  k_wd<<<256, 256, 0, stream>>>(W11, Wd, 256, 256);
  k_mm<<<dim3(4, NN/64), 256, 0, stream>>>(h1, Wd, b11, Abuf, NN, 256, 256, 0);
  k_mm<<<dim3(4, NN/64), 256, 0, stream>>>(h1, W11 + 256*256, nullptr, Pbuf, NN, 256, 256, 0);
  k_zero<<<2, 256, 0, stream>>>(ssum, 256); k_zero<<<2, 256, 0, stream>>>(ssq, 256);
  k_stats1<256><<<NN*KNN/128, 256, 0, stream>>>(Abuf, Pbuf, idx, ssum, ssq);
  k_bn_final<<<1, 256, 0, stream>>>(ssum, ssq, g11, be11, sbn, tbn, 256, invn);
  k_edge_mm<256><<<NN*KNN/32, 256, 0, stream>>>(Abuf, Pbuf, idx, sbn, tbn, W12, b12, out2);
  k_zero<<<2, 256, 0, stream>>>(ssum, 256); k_zero<<<2, 256, 0, stream>>>(ssq, 256);
  k_colstats<256><<<NN*KNN/256, 256, 0, stream>>>(out2, ssum, ssq);
  k_bn_final<<<1, 256, 0, stream>>>(ssum, ssq, g12, be12, sbn, tbn, 256, invn);
  k_maxpool<256><<<NN, 256, 0, stream>>>(out2, sbn, tbn, h2);

  // gconv2 -> h3
  k_agg<256><<<NN, 256, 0, stream>>>(h2, roff, csr, dout, din, xa);
  k_mm<<<dim3(4, NN/64), 256, 0, stream>>>(xa, Wc2, bc2, h3, NN, 256, 256, 1);

  // ---- edge conv 2 (input h3, 256 -> 64 -> 64) ----
  k_sq<<<NN/4, 256, 0, stream>>>(h3, sqv);
  k_split<<<NN, 256, 0, stream>>>(h3, xcat);
  k_gramtopk<<<dim3(SPL, NN/GT_RPB), 256, 0, stream>>>(xcat, sqv, pd, pi);
  k_knn_merge<<<NN/4, 256, 0, stream>>>(pd, pi, idx);
  k_wd<<<64, 256, 0, stream>>>(W21, Wd, 256, 64);
  k_mm<<<dim3(1, NN/64), 256, 0, stream>>>(h3, Wd, b21, Abuf, NN, 256, 64, 0);
  k_mm<<<dim3(1, NN/64), 256, 0, stream>>>(h3, W21 + 256*64, nullptr, Pbuf, NN, 256, 64, 0);
  k_zero<<<2, 256, 0, stream>>>(ssum, 256); k_zero<<<2, 256, 0, stream>>>(ssq, 256);
  k_stats1<64><<<NN*KNN/128, 256, 0, stream>>>(Abuf, Pbuf, idx, ssum, ssq);
  k_bn_final<<<1, 256, 0, stream>>>(ssum, ssq, g21, be21, sbn, tbn, 64, invn);
  k_edge_mm<64><<<NN*KNN/64, 256, 0, stream>>>(Abuf, Pbuf, idx, sbn, tbn, W22, b22, out2);
  k_zero<<<2, 256, 0, stream>>>(ssum, 256); k_zero<<<2, 256, 0, stream>>>(ssq, 256);
  k_colstats<64><<<NN*KNN/256, 256, 0, stream>>>(out2, ssum, ssq);
  k_bn_final<<<1, 256, 0, stream>>>(ssum, ssq, g22, be22, sbn, tbn, 64, invn);
  k_maxpool<64><<<NN/4, 256, 0, stream>>>(out2, sbn, tbn, h4);

  // gconv3 -> out
  k_agg<64><<<NN, 64, 0, stream>>>(h4, roff, csr, dout, din, xa);
  k_mm<<<dim3(1, NN/64), 256, 0, stream>>>(xa, Wc3, bc3, out, NN, 64, 32, 0);
}

// Round 9
// 2135.255 us; speedup vs baseline: 2.3406x; 2.3406x over previous
//
#include <hip/hip_runtime.h>

#define NN 8192
#define NE 131072
#define KNN 20
#define SPL 8            // kNN column splits (x-dim => XCD pinning)
#define CPS (NN/SPL)     // 1024 cols per split
#define GT_RPB 64        // gramtopk rows per block

typedef __attribute__((ext_vector_type(4))) float f32x4;
typedef __attribute__((ext_vector_type(8))) __bf16 bf16x8;

// ---------------- utility ----------------
__global__ void k_zero(float* p, int n){
  int i = blockIdx.x*256 + threadIdx.x;
  if (i < n) p[i] = 0.f;
}
__global__ void k_zero_i(int* p, int n){
  int i = blockIdx.x*256 + threadIdx.x;
  if (i < n) p[i] = 0;
}

__device__ __forceinline__ unsigned short f2bf(float x){
  unsigned u = __float_as_uint(x);
  unsigned r = (u + 0x7fff + ((u >> 16) & 1)) >> 16;
  return (unsigned short)r;
}
__device__ __forceinline__ float bf2f(unsigned short h){
  return __uint_as_float((unsigned)h << 16);
}

// ---------------- graph prep ----------------
__global__ void k_count(const int* __restrict__ src, const int* __restrict__ dst,
                        int* cs, int* cd){
  int e = blockIdx.x*256 + threadIdx.x;
  if (e < NE){ atomicAdd(&cs[src[e]], 1); atomicAdd(&cd[dst[e]], 1); }
}
__global__ void k_deg(const int* cs, const int* cd, float* dout, float* din){
  int i = blockIdx.x*256 + threadIdx.x;
  if (i < NN){
    dout[i] = rsqrtf((float)max(cs[i], 1));
    din[i]  = rsqrtf((float)max(cd[i], 1));
  }
}
__global__ void k_scan(const int* __restrict__ cnt, int* __restrict__ off){
  __shared__ int sh[256];
  __shared__ int carry;
  int tid = threadIdx.x;
  if (tid == 0) carry = 0;
  __syncthreads();
  for (int base = 0; base < NN; base += 256){
    int v = cnt[base + tid];
    int x = v;
    sh[tid] = x; __syncthreads();
    for (int o = 1; o < 256; o <<= 1){
      int y = (tid >= o) ? sh[tid - o] : 0;
      __syncthreads();
      x += y; sh[tid] = x;
      __syncthreads();
    }
    off[base + tid] = carry + x - v;
    __syncthreads();
    if (tid == 255){
      carry += x;
      if (base + 256 == NN) off[NN] = carry;
    }
    __syncthreads();
  }
}
__global__ void k_fill(const int* __restrict__ src, const int* __restrict__ dst,
                       const int* __restrict__ roff, int* cursor, int* csr){
  int e = blockIdx.x*256 + threadIdx.x;
  if (e < NE){
    int d = dst[e];
    int p = atomicAdd(&cursor[d], 1);
    csr[roff[d] + p] = src[e];
  }
}

// ---------------- gconv1 fused (3 -> 256) ----------------
__global__ void k_gconv1(const float* __restrict__ feat, const int* __restrict__ roff,
                         const int* __restrict__ csr, const float* __restrict__ dout,
                         const float* __restrict__ din, const float* __restrict__ Wc1,
                         const float* __restrict__ bc1, float* __restrict__ h1){
  int wid = threadIdx.x >> 6, lane = threadIdx.x & 63;
  int i = blockIdx.x*4 + wid;
  float a0=0.f, a1=0.f, a2=0.f;
  int beg = roff[i], end = roff[i+1];
  for (int t = beg + lane; t < end; t += 64){
    int s = csr[t]; float w = dout[s];
    a0 += feat[s*3+0]*w; a1 += feat[s*3+1]*w; a2 += feat[s*3+2]*w;
  }
  for (int m = 32; m; m >>= 1){
    a0 += __shfl_xor(a0, m); a1 += __shfl_xor(a1, m); a2 += __shfl_xor(a2, m);
  }
  float dn = din[i];
  a0 *= dn; a1 *= dn; a2 *= dn;
  for (int c = lane; c < 256; c += 64){
    float r = a0*Wc1[c] + a1*Wc1[256+c] + a2*Wc1[512+c] + bc1[c];
    h1[(size_t)i*256 + c] = fmaxf(r, 0.f);
  }
}

// ---------------- row squared norms (C=256) ----------------
__global__ void k_sq(const float* __restrict__ X, float* __restrict__ sq){
  int wid = threadIdx.x >> 6, lane = threadIdx.x & 63;
  int i = blockIdx.x*4 + wid;
  float4 v = *(const float4*)&X[(size_t)i*256 + lane*4];
  float s = v.x*v.x + v.y*v.y + v.z*v.z + v.w*v.w;
  for (int m = 32; m; m >>= 1) s += __shfl_xor(s, m);
  if (lane == 0) sq[i] = s;
}

// ---------------- split f32 -> [hi|lo] bf16, Xcat[n][512] ----------------
__global__ void k_split(const float* __restrict__ X, unsigned short* __restrict__ xcat){
  int row = blockIdx.x, c = threadIdx.x;
  float x = X[(size_t)row*256 + c];
  unsigned short h = f2bf(x);
  unsigned short lo = f2bf(x - bf2f(h));
  xcat[(size_t)row*512 + c] = h;
  xcat[(size_t)row*512 + 256 + c] = lo;
}

// ---------------- FUSED gram + top-K partial selection (v5) ----------------
// R8 post-mortem: float kd[20]; int ki[20] per-lane arrays were demoted to
// SCRATCH in every variant since R2 (R2's topk VGPR_Count=64 — too small to
// hold the 40-register list; MfmaUtil*dur == ideal MFMA time, rest is the
// scratch-bound scan at ~20x the issue model). v5: the top-20 list lives in
// 40 NAMED SCALAR variables (kd0..kd19 / ki0..ki19) with a macro-generated
// swap chain — every access statically indexed, nothing demotable.
// Geometry identical to v4: block = 64 rows x one 1024-col split; wave =
// 32x64 sub-tile; lane owns (row, 32-col quarter) = 256 candidates.
// Exactness: any true row-top-20 elem has <=19 row elems smaller, hence
// <=19 subset elems smaller -> survives its lane's top-20; merges use
// (val,idx); in-lane strict-< keeps equal values in ascending-index order.
__global__ __launch_bounds__(256, 2)
void k_gramtopk(const unsigned short* __restrict__ Xcat, const float* __restrict__ sq,
                float* __restrict__ pd, int* __restrict__ pi){
  __shared__ float tile[GT_RPB][132];   // 33.8 KB keys
  __shared__ float sqr[GT_RPB];
  __shared__ float sqc[128];

  int tid = threadIdx.x;
  int lw = tid >> 6, l = tid & 63;
  int split = blockIdx.x;          // x fastest => bid%8 = split => XCD pinning
  int rb = blockIdx.y*GT_RPB;
  int cb0 = split*CPS;

  if (tid < GT_RPB) sqr[tid] = sq[rb + tid];

  // wave tile geometry: 4 waves = 2(m) x 2(n), each 32 rows x 64 cols
  int wm = lw >> 1, wn = lw & 1;
  int fm = l & 15, kg = l >> 4;

  // global fragment base pointers (in shorts); imm offsets cover k within row
  const unsigned short* aptr0 = Xcat + (size_t)(rb + wm*32 +  0 + fm)*512 + kg*8;
  const unsigned short* aptr1 = Xcat + (size_t)(rb + wm*32 + 16 + fm)*512 + kg*8;
  const unsigned short* bptr[4];
  #pragma unroll
  for (int nf = 0; nf < 4; nf++)
    bptr[nf] = Xcat + (size_t)(cb0 + wn*64 + nf*16 + fm)*512 + kg*8;

  // per-lane topk state: lane owns (row = tid>>2, quarter q = tid&3 -> 32 cols)
  int myrow = tid >> 2, q = tid & 3;
  float kd0=INFINITY,kd1=INFINITY,kd2=INFINITY,kd3=INFINITY,kd4=INFINITY,
        kd5=INFINITY,kd6=INFINITY,kd7=INFINITY,kd8=INFINITY,kd9=INFINITY,
        kd10=INFINITY,kd11=INFINITY,kd12=INFINITY,kd13=INFINITY,kd14=INFINITY,
        kd15=INFINITY,kd16=INFINITY,kd17=INFINITY,kd18=INFINITY,kd19=INFINITY;
  int ki0=0x7fffffff,ki1=0x7fffffff,ki2=0x7fffffff,ki3=0x7fffffff,ki4=0x7fffffff,
      ki5=0x7fffffff,ki6=0x7fffffff,ki7=0x7fffffff,ki8=0x7fffffff,ki9=0x7fffffff,
      ki10=0x7fffffff,ki11=0x7fffffff,ki12=0x7fffffff,ki13=0x7fffffff,ki14=0x7fffffff,
      ki15=0x7fffffff,ki16=0x7fffffff,ki17=0x7fffffff,ki18=0x7fffffff,ki19=0x7fffffff;

#define ST(U) { bool sw = nk < kd##U; float tv = kd##U; int tq = ki##U; \
      if (sw){ kd##U = nk; ki##U = ni; nk = tv; ni = tq; } }
#define INSE(kc, jc) { if ((kc) < kd19){ float nk = (kc); int ni = (jc); \
      ST(0) ST(1) ST(2) ST(3) ST(4) ST(5) ST(6) ST(7) ST(8) ST(9) \
      ST(10) ST(11) ST(12) ST(13) ST(14) ST(15) ST(16) ST(17) ST(18) ST(19) } }

  #pragma unroll 1
  for (int ct = 0; ct < CPS/128; ct++){
    if (tid < 128) sqc[tid] = sq[cb0 + ct*128 + tid];

    f32x4 acc[2][4];
    #pragma unroll
    for (int m = 0; m < 2; m++)
      #pragma unroll
      for (int n = 0; n < 4; n++) acc[m][n] = (f32x4){0.f,0.f,0.f,0.f};

    // K-loop: 24 mfma-K-steps of 32; sections A{hi,lo,hi} x B{hi,hi,lo}.
    // No barriers, no LDS: pure load->MFMA, compiler-pipelined.
    #pragma unroll 2
    for (int t = 0; t < 24; t++){
      int sec = t >> 3;
      int k0 = (t & 7)*32;
      int ka = ((sec == 1) ? 256 : 0) + k0;   // shorts
      int kb = ((sec == 2) ? 256 : 0) + k0;
      bf16x8 a0 = *(const bf16x8*)(aptr0 + ka);
      bf16x8 a1 = *(const bf16x8*)(aptr1 + ka);
      #pragma unroll
      for (int nf = 0; nf < 4; nf++){
        bf16x8 b = *(const bf16x8*)(bptr[nf] + kb);
        acc[0][nf] = __builtin_amdgcn_mfma_f32_16x16x32_bf16(a0, b, acc[0][nf], 0, 0, 0);
        acc[1][nf] = __builtin_amdgcn_mfma_f32_16x16x32_bf16(a1, b, acc[1][nf], 0, 0, 0);
      }
    }
    #pragma unroll
    for (int nf = 0; nf < 4; nf++) bptr[nf] += 128*512;   // next 128 B-rows

    __syncthreads();   // previous ct's scan done before tile overwrite

    // keys into tile. C/D: col = lane&15, row = (lane>>4)*4 + reg
    #pragma unroll
    for (int mf = 0; mf < 2; mf++){
      #pragma unroll
      for (int nf = 0; nf < 4; nf++){
        int ocol = wn*64 + nf*16 + fm;
        float sc = sqc[ocol];
        #pragma unroll
        for (int r = 0; r < 4; r++){
          int orow = wm*32 + mf*16 + kg*4 + r;
          tile[orow][ocol] = (sqr[orow] + sc) - 2.f*acc[mf][nf][r];
        }
      }
    }
    __syncthreads();

    // scan own (row, quarter): 8 steps x 4 keys, straight-line insertion
    int jb0 = cb0 + ct*128 + q*32;
    #pragma unroll 1
    for (int st = 0; st < 8; st++){
      float4 kv = *(const float4*)&tile[myrow][q*32 + st*4];
      int jb = jb0 + st*4;
      float t19 = kd19;
      float mn = fminf(fminf(kv.x, kv.y), fminf(kv.z, kv.w));
      if (__any(mn < t19)){
        INSE(kv.x, jb+0);
        INSE(kv.y, jb+1);
        INSE(kv.z, jb+2);
        INSE(kv.w, jb+3);
      }
    }
  }
#undef INSE
#undef ST

  // 4-lane (quarter-group) merge: pop global min 20x -> sorted list per (row,split)
#define MV(A,B) { kd##A = kd##B; ki##A = ki##B; }
  size_t base = ((size_t)(rb + myrow)*SPL + split)*20;
  #pragma unroll 1
  for (int r = 0; r < KNN; r++){
    float bv = kd0; int bi = ki0;
    #pragma unroll
    for (int m = 1; m <= 2; m <<= 1){
      float ov = __shfl_xor(bv, m); int oi = __shfl_xor(bi, m);
      if (ov < bv || (ov == bv && oi < bi)){ bv = ov; bi = oi; }
    }
    if (ki0 == bi){   // winner (col idx unique)
      MV(0,1) MV(1,2) MV(2,3) MV(3,4) MV(4,5) MV(5,6) MV(6,7) MV(7,8) MV(8,9) MV(9,10)
      MV(10,11) MV(11,12) MV(12,13) MV(13,14) MV(14,15) MV(15,16) MV(16,17) MV(17,18) MV(18,19)
      kd19 = INFINITY; ki19 = 0x7fffffff;
    }
    if (q == 0){ pd[base + r] = bv; pi[base + r] = bi; }
  }
#undef MV
}

// ---------------- merge 8 sorted 20-lists/row -> exact top-20 ----------------
__global__ __launch_bounds__(256)
void k_knn_merge(const float* __restrict__ pd, const int* __restrict__ pi,
                 int* __restrict__ idxo){
  int tid = threadIdx.x, lw = tid >> 6, l = tid & 63;
  int row = blockIdx.x*4 + lw;
  float v0, v1, v2, v3, v4; int i0, i1, i2, i3, i4;
  if (l < 32){
    size_t base = (size_t)row*(SPL*20) + (l >> 2)*20 + (l & 3)*5;  // sorted chunk
    v0 = pd[base+0]; v1 = pd[base+1]; v2 = pd[base+2]; v3 = pd[base+3]; v4 = pd[base+4];
    i0 = pi[base+0]; i1 = pi[base+1]; i2 = pi[base+2]; i3 = pi[base+3]; i4 = pi[base+4];
  } else {
    v0 = v1 = v2 = v3 = v4 = INFINITY;
    i0 = i1 = i2 = i3 = i4 = 0x7fffffff;
  }
  #pragma unroll 1
  for (int r = 0; r < KNN; r++){
    float bv = v0; int bi = i0;
    #pragma unroll
    for (int mm = 32; mm; mm >>= 1){
      float ov = __shfl_xor(bv, mm); int oi = __shfl_xor(bi, mm);
      if (ov < bv || (ov == bv && oi < bi)){ bv = ov; bi = oi; }
    }
    if (i0 == bi){ v0=v1;i0=i1; v1=v2;i1=i2; v2=v3;i2=i3; v3=v4;i3=i4; v4=INFINITY; i4=0x7fffffff; }
    if (l == 0) idxo[(size_t)row*KNN + r] = bi;
  }
}

// ---------------- Wd = Wtop - Wbot ----------------
__global__ void k_wd(const float* __restrict__ W, float* __restrict__ Wd, int rows, int M){
  int t = blockIdx.x*256 + threadIdx.x;
  if (t < rows*M) Wd[t] = W[t] - W[rows*M + t];
}

// ---------------- generic tiled matmul: C = A(nxK) @ B(KxM) [+bias][relu] ----------------
__global__ __launch_bounds__(256)
void k_mm(const float* __restrict__ A, const float* __restrict__ B,
          const float* __restrict__ bias, float* __restrict__ Cout,
          int n, int Kd, int M, int relu){
  __shared__ float la[16][68], lb[16][68];
  int tid = threadIdx.x;
  int rb = blockIdx.y*64, cb = blockIdx.x*64;
  int lr = tid >> 2, lq = (tid & 3)*4;
  int ty = tid >> 4, tx = tid & 15;
  float acc[4][4] = {};
  for (int k0 = 0; k0 < Kd; k0 += 16){
    __syncthreads();
    #pragma unroll
    for (int u = 0; u < 4; u++){
      int k = k0 + lq + u;
      la[lq+u][lr] = (k < Kd) ? A[(size_t)(rb+lr)*Kd + k] : 0.f;
    }
    int kk = tid >> 4; int cc = (tid & 15)*4;
    #pragma unroll
    for (int u = 0; u < 4; u++){
      int c = cb + cc + u; int k = k0 + kk;
      lb[kk][cc+u] = (k < Kd && c < M) ? B[(size_t)k*M + c] : 0.f;
    }
    __syncthreads();
    #pragma unroll
    for (int k = 0; k < 16; k++){
      float4 a = *(const float4*)&la[k][ty*4];
      float4 b = *(const float4*)&lb[k][tx*4];
      float avv[4] = {a.x,a.y,a.z,a.w}, bvv[4] = {b.x,b.y,b.z,b.w};
      #pragma unroll
      for (int u = 0; u < 4; u++)
        #pragma unroll
        for (int v = 0; v < 4; v++) acc[u][v] += avv[u]*bvv[v];
    }
  }
  #pragma unroll
  for (int u = 0; u < 4; u++){
    int r = rb + ty*4 + u;
    #pragma unroll
    for (int v = 0; v < 4; v++){
      int c = cb + tx*4 + v;
      if (c < M){
        float x = acc[u][v] + (bias ? bias[c] : 0.f);
        if (relu) x = fmaxf(x, 0.f);
        Cout[(size_t)r*M + c] = x;
      }
    }
  }
}

// ---------------- stats over A[i]+P[j] per channel ----------------
template<int C>
__global__ __launch_bounds__(256)
void k_stats1(const float* __restrict__ A, const float* __restrict__ P,
              const int* __restrict__ idx, float* __restrict__ ssum, float* __restrict__ ssq){
  __shared__ int si[128], sj[128];
  int tid = threadIdx.x;
  int s0 = blockIdx.x*128;
  if (tid < 128){ si[tid] = (s0 + tid)/KNN; sj[tid] = idx[s0 + tid]; }
  __syncthreads();
  constexpr int MPAR = 256/C;
  int tc = tid % C, sr = tid / C;
  float s = 0.f, q = 0.f;
  for (int m = sr; m < 128; m += MPAR){
    float v = A[(size_t)si[m]*C + tc] + P[(size_t)sj[m]*C + tc];
    s += v; q += v*v;
  }
  if constexpr (MPAR > 1){
    __shared__ float rs[256], rq[256];
    rs[tid] = s; rq[tid] = q; __syncthreads();
    if (sr == 0){
      for (int u = 1; u < MPAR; u++){ s += rs[u*C + tc]; q += rq[u*C + tc]; }
    }
  }
  if (sr == 0){ atomicAdd(&ssum[tc], s); atomicAdd(&ssq[tc], q); }
}

// ---------------- column stats over dense X (rows = N*KNN) ----------------
template<int C>
__global__ __launch_bounds__(256)
void k_colstats(const float* __restrict__ X, float* __restrict__ ssum, float* __restrict__ ssq){
  constexpr int MPAR = 256/C;
  int tid = threadIdx.x;
  int tc = tid % C, sr = tid / C;
  int base = blockIdx.x*256;
  float s = 0.f, q = 0.f;
  for (int m = sr; m < 256; m += MPAR){
    float v = X[(size_t)(base + m)*C + tc];
    s += v; q += v*v;
  }
  if constexpr (MPAR > 1){
    __shared__ float rs[256], rq[256];
    rs[tid] = s; rq[tid] = q; __syncthreads();
    if (sr == 0){
      for (int u = 1; u < MPAR; u++){ s += rs[u*C + tc]; q += rq[u*C + tc]; }
    }
  }
  if (sr == 0){ atomicAdd(&ssum[tc], s); atomicAdd(&ssq[tc], q); }
}

__global__ void k_bn_final(const float* __restrict__ ssum, const float* __restrict__ ssq,
                           const float* __restrict__ g, const float* __restrict__ be,
                           float* __restrict__ sb, float* __restrict__ tb, int C, float invn){
  int c = threadIdx.x;
  if (c < C){
    float mu = ssum[c]*invn;
    float var = fmaxf(ssq[c]*invn - mu*mu, 0.f);
    float s = g[c]*rsqrtf(var + 1e-5f);
    sb[c] = s; tb[c] = be[c] - mu*s;
  }
}

// ---------------- per-edge matmul: out = relu(bn1(A[i]+P[j])) @ W + bias ----------------
template<int C>
__global__ __launch_bounds__(256)
void k_edge_mm(const float* __restrict__ A, const float* __restrict__ P,
               const int* __restrict__ idx, const float* __restrict__ sb,
               const float* __restrict__ tb, const float* __restrict__ W,
               const float* __restrict__ bias, float* __restrict__ out){
  constexpr int BM   = (C == 256) ? 32 : 64;
  constexpr int KT   = (C == 256) ? 16 : 64;
  constexpr int COLG = C/8;
  constexpr int ROWG = 256/COLG;
  constexpr int EPT  = BM/ROWG;
  constexpr int MPAR = 256/C;
  __shared__ float e2[BM][C+1];
  __shared__ float wt[KT][C+4];
  __shared__ int sj[BM];
  int tid = threadIdx.x;
  int s0 = blockIdx.x*BM;
  if (tid < BM) sj[tid] = idx[s0 + tid];
  __syncthreads();
  for (int mb = 0; mb < BM; mb += MPAR){
    int m = mb + tid / C;
    int c = tid % C;
    int i = (s0 + m)/KNN;
    int j = sj[m];
    float v = (A[(size_t)i*C + c] + P[(size_t)j*C + c])*sb[c] + tb[c];
    e2[m][c] = fmaxf(v, 0.f);
  }
  float acc[EPT][8];
  #pragma unroll
  for (int m = 0; m < EPT; m++)
    #pragma unroll
    for (int u = 0; u < 8; u++) acc[m][u] = 0.f;
  int tr = tid / COLG, tc = tid % COLG;
  for (int kt = 0; kt < C; kt += KT){
    __syncthreads();
    for (int t = tid; t < KT*C; t += 256){
      wt[t / C][t % C] = W[(size_t)(kt + t/C)*C + (t % C)];
    }
    __syncthreads();
    #pragma unroll 4
    for (int k = 0; k < KT; k++){
      float4 w0 = *(const float4*)&wt[k][tc*8];
      float4 w1 = *(const float4*)&wt[k][tc*8 + 4];
      float b[8] = {w0.x,w0.y,w0.z,w0.w,w1.x,w1.y,w1.z,w1.w};
      #pragma unroll
      for (int m = 0; m < EPT; m++){
        float a = e2[tr*EPT + m][kt + k];
        #pragma unroll
        for (int u = 0; u < 8; u++) acc[m][u] += a*b[u];
      }
    }
  }
  #pragma unroll
  for (int m = 0; m < EPT; m++){
    int row = s0 + tr*EPT + m;
    float4 o0, o1;
    o0.x = acc[m][0] + bias[tc*8+0]; o0.y = acc[m][1] + bias[tc*8+1];
    o0.z = acc[m][2] + bias[tc*8+2]; o0.w = acc[m][3] + bias[tc*8+3];
    o1.x = acc[m][4] + bias[tc*8+4]; o1.y = acc[m][5] + bias[tc*8+5];
    o1.z = acc[m][6] + bias[tc*8+6]; o1.w = acc[m][7] + bias[tc*8+7];
    *(float4*)&out[(size_t)row*C + tc*8]     = o0;
    *(float4*)&out[(size_t)row*C + tc*8 + 4] = o1;
  }
}

// ---------------- bn2 + relu + max over K ----------------
template<int C>
__global__ void k_maxpool(const float* __restrict__ X, const float* __restrict__ sb,
                          const float* __restrict__ tb, float* __restrict__ H){
  constexpr int NPB = 256/C;
  int node = blockIdx.x*NPB + threadIdx.x / C;
  int c = threadIdx.x % C;
  float s = sb[c], t = tb[c];
  float mx = 0.f;
  for (int k = 0; k < KNN; k++){
    float v = X[(size_t)(node*KNN + k)*C + c]*s + t;
    mx = fmaxf(mx, v);
  }
  H[(size_t)node*C + c] = mx;
}

// ---------------- gconv aggregation ----------------
template<int C>
__global__ void k_agg(const float* __restrict__ X, const int* __restrict__ roff,
                      const int* __restrict__ csr, const float* __restrict__ dout,
                      const float* __restrict__ din, float* __restrict__ XA){
  int i = blockIdx.x; int c = threadIdx.x;
  float acc = 0.f;
  int b = roff[i], e = roff[i+1];
  for (int t = b; t < e; t++){
    int s = csr[t];
    acc += X[(size_t)s*C + c]*dout[s];
  }
  XA[(size_t)i*C + c] = acc*din[i];
}

// ================= host =================
extern "C" void kernel_launch(void* const* d_in, const int* in_sizes, int n_in,
                              void* d_out, int out_size, void* d_ws, size_t ws_size,
                              hipStream_t stream){
  const float* feat = (const float*)d_in[0];
  const int*   src  = (const int*)d_in[1];
  const int*   dst  = (const int*)d_in[2];
  const float* Wc1  = (const float*)d_in[3];
  const float* bc1  = (const float*)d_in[4];
  const float* Wc2  = (const float*)d_in[5];
  const float* bc2  = (const float*)d_in[6];
  const float* Wc3  = (const float*)d_in[7];
  const float* bc3  = (const float*)d_in[8];
  const float* W11  = (const float*)d_in[9];
  const float* b11  = (const float*)d_in[10];
  const float* g11  = (const float*)d_in[11];
  const float* be11 = (const float*)d_in[12];
  const float* W12  = (const float*)d_in[13];
  const float* b12  = (const float*)d_in[14];
  const float* g12  = (const float*)d_in[15];
  const float* be12 = (const float*)d_in[16];
  const float* W21  = (const float*)d_in[17];
  const float* b21  = (const float*)d_in[18];
  const float* g21  = (const float*)d_in[19];
  const float* be21 = (const float*)d_in[20];
  const float* W22  = (const float*)d_in[21];
  const float* b22  = (const float*)d_in[22];
  const float* g22  = (const float*)d_in[23];
  const float* be22 = (const float*)d_in[24];
  float* out = (float*)d_out;

  char* w = (char*)d_ws; size_t off = 0;
  auto alloc = [&](size_t bytes)->void*{
    void* p = w + off;
    off += bytes; off = (off + 255) & ~(size_t)255;
    return p;
  };
  int* cnt_s  = (int*)alloc(NN*4);
  int* cnt_d  = (int*)alloc(NN*4);
  int* roff   = (int*)alloc((NN+1)*4);
  int* cursor = (int*)alloc(NN*4);
  int* csr    = (int*)alloc(NE*4);
  int* idx    = (int*)alloc((size_t)NN*KNN*4);
  float* dout = (float*)alloc(NN*4);
  float* din  = (float*)alloc(NN*4);
  float* sqv  = (float*)alloc(NN*4);
  float* h1   = (float*)alloc((size_t)NN*256*4);
  float* h2   = (float*)alloc((size_t)NN*256*4);
  float* h3   = (float*)alloc((size_t)NN*256*4);
  float* h4   = (float*)alloc((size_t)NN*64*4);
  float* xa   = (float*)alloc((size_t)NN*256*4);
  float* Abuf = (float*)alloc((size_t)NN*256*4);
  float* Pbuf = (float*)alloc((size_t)NN*256*4);
  float* Wd   = (float*)alloc(256*256*4);
  float* ssum = (float*)alloc(256*4);
  float* ssq  = (float*)alloc(256*4);
  float* sbn  = (float*)alloc(256*4);
  float* tbn  = (float*)alloc(256*4);
  float* out2 = (float*)alloc((size_t)NN*KNN*256*4);   // 167.8 MB
  // kNN scratch aliases out2 (consumed before edge_mm writes out2):
  float* pd = out2;                                           // NN*SPL*20*4 = 5.24 MB
  int*   pi = (int*)(out2 + (size_t)NN*SPL*20);               // 5.24 MB
  unsigned short* xcat = (unsigned short*)((char*)pi + (size_t)NN*SPL*20*4);  // 8.4 MB
  (void)ws_size; (void)n_in; (void)in_sizes; (void)out_size;

  const float invn = 1.0f / (float)(NN*KNN);

  // graph prep
  k_zero_i<<<32, 256, 0, stream>>>(cnt_s, NN);
  k_zero_i<<<32, 256, 0, stream>>>(cnt_d, NN);
  k_zero_i<<<32, 256, 0, stream>>>(cursor, NN);
  k_count<<<NE/256, 256, 0, stream>>>(src, dst, cnt_s, cnt_d);
  k_deg<<<32, 256, 0, stream>>>(cnt_s, cnt_d, dout, din);
  k_scan<<<1, 256, 0, stream>>>(cnt_d, roff);
  k_fill<<<NE/256, 256, 0, stream>>>(src, dst, roff, cursor, csr);

  // gconv1 -> h1
  k_gconv1<<<NN/4, 256, 0, stream>>>(feat, roff, csr, dout, din, Wc1, bc1, h1);

  // ---- edge conv 1 (input h1, 256 -> 256 -> 256) ----
  k_sq<<<NN/4, 256, 0, stream>>>(h1, sqv);
  k_split<<<NN, 256, 0, stream>>>(h1, xcat);
  k_gramtopk<<<dim3(SPL, NN/GT_RPB), 256, 0, stream>>>(xcat, sqv, pd, pi);
  k_knn_merge<<<NN/4, 256, 0, stream>>>(pd, pi, idx);
  k_wd<<<256, 256, 0, stream>>>(W11, Wd, 256, 256);
  k_mm<<<dim3(4, NN/64), 256, 0, stream>>>(h1, Wd, b11, Abuf, NN, 256, 256, 0);
  k_mm<<<dim3(4, NN/64), 256, 0, stream>>>(h1, W11 + 256*256, nullptr, Pbuf, NN, 256, 256, 0);
  k_zero<<<2, 256, 0, stream>>>(ssum, 256); k_zero<<<2, 256, 0, stream>>>(ssq, 256);
  k_stats1<256><<<NN*KNN/128, 256, 0, stream>>>(Abuf, Pbuf, idx, ssum, ssq);
  k_bn_final<<<1, 256, 0, stream>>>(ssum, ssq, g11, be11, sbn, tbn, 256, invn);
  k_edge_mm<256><<<NN*KNN/32, 256, 0, stream>>>(Abuf, Pbuf, idx, sbn, tbn, W12, b12, out2);
  k_zero<<<2, 256, 0, stream>>>(ssum, 256); k_zero<<<2, 256, 0, stream>>>(ssq, 256);
  k_colstats<256><<<NN*KNN/256, 256, 0, stream>>>(out2, ssum, ssq);
  k_bn_final<<<1, 256, 0, stream>>>(ssum, ssq, g12, be12, sbn, tbn, 256, invn);
  k_maxpool<256><<<NN, 256, 0, stream>>>(out2, sbn, tbn, h2);

  // gconv2 -> h3
  k_agg<256><<<NN, 256, 0, stream>>>(h2, roff, csr, dout, din, xa);
  k_mm<<<dim3(4, NN/64), 256, 0, stream>>>(xa, Wc2, bc2, h3, NN, 256, 256, 1);

  // ---- edge conv 2 (input h3, 256 -> 64 -> 64) ----
  k_sq<<<NN/4, 256, 0, stream>>>(h3, sqv);
  k_split<<<NN, 256, 0, stream>>>(h3, xcat);
  k_gramtopk<<<dim3(SPL, NN/GT_RPB), 256, 0, stream>>>(xcat, sqv, pd, pi);
  k_knn_merge<<<NN/4, 256, 0, stream>>>(pd, pi, idx);
  k_wd<<<64, 256, 0, stream>>>(W21, Wd, 256, 64);
  k_mm<<<dim3(1, NN/64), 256, 0, stream>>>(h3, Wd, b21, Abuf, NN, 256, 64, 0);
  k_mm<<<dim3(1, NN/64), 256, 0, stream>>>(h3, W21 + 256*64, nullptr, Pbuf, NN, 256, 64, 0);
  k_zero<<<2, 256, 0, stream>>>(ssum, 256); k_zero<<<2, 256, 0, stream>>>(ssq, 256);
  k_stats1<64><<<NN*KNN/128, 256, 0, stream>>>(Abuf, Pbuf, idx, ssum, ssq);
  k_bn_final<<<1, 256, 0, stream>>>(ssum, ssq, g21, be21, sbn, tbn, 64, invn);
  k_edge_mm<64><<<NN*KNN/64, 256, 0, stream>>>(Abuf, Pbuf, idx, sbn, tbn, W22, b22, out2);
  k_zero<<<2, 256, 0, stream>>>(ssum, 256); k_zero<<<2, 256, 0, stream>>>(ssq, 256);
  k_colstats<64><<<NN*KNN/256, 256, 0, stream>>>(out2, ssum, ssq);
  k_bn_final<<<1, 256, 0, stream>>>(ssum, ssq, g22, be22, sbn, tbn, 64, invn);
  k_maxpool<64><<<NN/4, 256, 0, stream>>>(out2, sbn, tbn, h4);

  // gconv3 -> out
  k_agg<64><<<NN, 64, 0, stream>>>(h4, roff, csr, dout, din, xa);
  k_mm<<<dim3(1, NN/64), 256, 0, stream>>>(xa, Wc3, bc3, out, NN, 64, 32, 0);
}

// Round 10
// 1603.840 us; speedup vs baseline: 3.1161x; 1.3313x over previous
//
#include <hip/hip_runtime.h>

#define NN 8192
#define NE 131072
#define KNN 20
#define CH 4096   // gram chunk rows
#define GBM 128
#define GBN 128
#define GBK 64

typedef __attribute__((ext_vector_type(4))) float f32x4;
typedef __attribute__((ext_vector_type(8))) __bf16 bf16x8;

// ---------------- utility ----------------
__global__ void k_zero(float* p, int n){
  int i = blockIdx.x*256 + threadIdx.x;
  if (i < n) p[i] = 0.f;
}
__global__ void k_zero_i(int* p, int n){
  int i = blockIdx.x*256 + threadIdx.x;
  if (i < n) p[i] = 0;
}

__device__ __forceinline__ unsigned short f2bf(float x){
  unsigned u = __float_as_uint(x);
  unsigned r = (u + 0x7fff + ((u >> 16) & 1)) >> 16;
  return (unsigned short)r;
}
__device__ __forceinline__ float bf2f(unsigned short h){
  return __uint_as_float((unsigned)h << 16);
}
__device__ __forceinline__ void gload16(const void* g, void* l){
  __builtin_amdgcn_global_load_lds(
      (const __attribute__((address_space(1))) void*)g,
      (__attribute__((address_space(3))) void*)l, 16, 0, 0);
}

// ---------------- graph prep ----------------
__global__ void k_count(const int* __restrict__ src, const int* __restrict__ dst,
                        int* cs, int* cd){
  int e = blockIdx.x*256 + threadIdx.x;
  if (e < NE){ atomicAdd(&cs[src[e]], 1); atomicAdd(&cd[dst[e]], 1); }
}
__global__ void k_deg(const int* cs, const int* cd, float* dout, float* din){
  int i = blockIdx.x*256 + threadIdx.x;
  if (i < NN){
    dout[i] = rsqrtf((float)max(cs[i], 1));
    din[i]  = rsqrtf((float)max(cd[i], 1));
  }
}
__global__ void k_scan(const int* __restrict__ cnt, int* __restrict__ off){
  __shared__ int sh[256];
  __shared__ int carry;
  int tid = threadIdx.x;
  if (tid == 0) carry = 0;
  __syncthreads();
  for (int base = 0; base < NN; base += 256){
    int v = cnt[base + tid];
    int x = v;
    sh[tid] = x; __syncthreads();
    for (int o = 1; o < 256; o <<= 1){
      int y = (tid >= o) ? sh[tid - o] : 0;
      __syncthreads();
      x += y; sh[tid] = x;
      __syncthreads();
    }
    off[base + tid] = carry + x - v;
    __syncthreads();
    if (tid == 255){
      carry += x;
      if (base + 256 == NN) off[NN] = carry;
    }
    __syncthreads();
  }
}
__global__ void k_fill(const int* __restrict__ src, const int* __restrict__ dst,
                       const int* __restrict__ roff, int* cursor, int* csr){
  int e = blockIdx.x*256 + threadIdx.x;
  if (e < NE){
    int d = dst[e];
    int p = atomicAdd(&cursor[d], 1);
    csr[roff[d] + p] = src[e];
  }
}

// ---------------- gconv1 fused (3 -> 256) ----------------
__global__ void k_gconv1(const float* __restrict__ feat, const int* __restrict__ roff,
                         const int* __restrict__ csr, const float* __restrict__ dout,
                         const float* __restrict__ din, const float* __restrict__ Wc1,
                         const float* __restrict__ bc1, float* __restrict__ h1){
  int wid = threadIdx.x >> 6, lane = threadIdx.x & 63;
  int i = blockIdx.x*4 + wid;
  float a0=0.f, a1=0.f, a2=0.f;
  int beg = roff[i], end = roff[i+1];
  for (int t = beg + lane; t < end; t += 64){
    int s = csr[t]; float w = dout[s];
    a0 += feat[s*3+0]*w; a1 += feat[s*3+1]*w; a2 += feat[s*3+2]*w;
  }
  for (int m = 32; m; m >>= 1){
    a0 += __shfl_xor(a0, m); a1 += __shfl_xor(a1, m); a2 += __shfl_xor(a2, m);
  }
  float dn = din[i];
  a0 *= dn; a1 *= dn; a2 *= dn;
  for (int c = lane; c < 256; c += 64){
    float r = a0*Wc1[c] + a1*Wc1[256+c] + a2*Wc1[512+c] + bc1[c];
    h1[(size_t)i*256 + c] = fmaxf(r, 0.f);
  }
}

// ---------------- row squared norms (C=256) ----------------
__global__ void k_sq(const float* __restrict__ X, float* __restrict__ sq){
  int wid = threadIdx.x >> 6, lane = threadIdx.x & 63;
  int i = blockIdx.x*4 + wid;
  float4 v = *(const float4*)&X[(size_t)i*256 + lane*4];
  float s = v.x*v.x + v.y*v.y + v.z*v.z + v.w*v.w;
  for (int m = 32; m; m >>= 1) s += __shfl_xor(s, m);
  if (lane == 0) sq[i] = s;
}

// ---------------- split f32 -> [hi|lo] bf16, Xcat[n][512] ----------------
__global__ void k_split(const float* __restrict__ X, unsigned short* __restrict__ xcat){
  int row = blockIdx.x, c = threadIdx.x;
  float x = X[(size_t)row*256 + c];
  unsigned short h = f2bf(x);
  unsigned short lo = f2bf(x - bf2f(h));
  xcat[(size_t)row*512 + c] = h;
  xcat[(size_t)row*512 + 256 + c] = lo;
}

// ---------------- MFMA gram: G[chunk row][j] = x_i . x_j (split bf16, K=768) ----------------
// A sections: {hi, lo, hi}; B sections: {hi, hi, lo}  (R2-verified kernel)
__global__ __launch_bounds__(256)
void k_gram_mfma(const unsigned short* __restrict__ Xcat,
                 float* __restrict__ G, int r0){
  __shared__ unsigned short sA[GBM*GBK];  // 16 KB, swizzled granules
  __shared__ unsigned short sB[GBM*GBK];
  int tid = threadIdx.x;
  int lw = tid >> 6, l = tid & 63;
  int rbl = blockIdx.y*GBM;      // local chunk row base
  int rb = r0 + rbl;             // global source row base (A)
  int cb = blockIdx.x*GBN;       // global source row base (B) = G column base

  int srow = l >> 3;             // 0..7
  int scol = (l & 7) ^ srow;     // swizzled source granule (row&7 == srow)
  const unsigned short* srcA[4];
  const unsigned short* srcB[4];
  char* dstA[4]; char* dstB[4];
  #pragma unroll
  for (int i = 0; i < 4; i++){
    int c = lw*4 + i;
    int row = c*8 + srow;
    srcA[i] = Xcat + (size_t)(rb + row)*512 + scol*8;
    srcB[i] = Xcat + (size_t)(cb + row)*512 + scol*8;
    dstA[i] = (char*)sA + c*1024;
    dstB[i] = (char*)sB + c*1024;
  }

  int wm = lw >> 1, wn = lw & 1;
  int fm = l & 15, kg = l >> 4;
  unsigned offA[4][2], offB[4][2];
  #pragma unroll
  for (int mf = 0; mf < 4; mf++){
    int rowa = wm*64 + mf*16 + fm;
    int rowb = wn*64 + mf*16 + fm;
    #pragma unroll
    for (int ks = 0; ks < 2; ks++){
      offA[mf][ks] = rowa*128 + (((unsigned)(ks*4 + kg) ^ (rowa & 7)))*16;
      offB[mf][ks] = rowb*128 + (((unsigned)(ks*4 + kg) ^ (rowb & 7)))*16;
    }
  }

  f32x4 acc[4][4];
  #pragma unroll
  for (int m = 0; m < 4; m++)
    #pragma unroll
    for (int n = 0; n < 4; n++) acc[m][n] = (f32x4){0.f,0.f,0.f,0.f};

  #pragma unroll
  for (int s = 0; s < 12; s++){
    int sec = s >> 2;
    int inner = (s & 3)*64;
    int cbA = (sec == 1 ? 256 : 0) + inner;
    int cbB = (sec == 2 ? 256 : 0) + inner;
    #pragma unroll
    for (int i = 0; i < 4; i++){
      gload16(srcA[i] + cbA, dstA[i]);
      gload16(srcB[i] + cbB, dstB[i]);
    }
    __syncthreads();
    #pragma unroll
    for (int ks = 0; ks < 2; ks++){
      bf16x8 a[4], b[4];
      #pragma unroll
      for (int mf = 0; mf < 4; mf++) a[mf] = *(const bf16x8*)((const char*)sA + offA[mf][ks]);
      #pragma unroll
      for (int nf = 0; nf < 4; nf++) b[nf] = *(const bf16x8*)((const char*)sB + offB[nf][ks]);
      #pragma unroll
      for (int mf = 0; mf < 4; mf++)
        #pragma unroll
        for (int nf = 0; nf < 4; nf++)
          acc[mf][nf] = __builtin_amdgcn_mfma_f32_16x16x32_bf16(a[mf], b[nf], acc[mf][nf], 0, 0, 0);
    }
    __syncthreads();
  }

  #pragma unroll
  for (int mf = 0; mf < 4; mf++){
    int orow = rbl + wm*64 + mf*16 + kg*4;
    #pragma unroll
    for (int nf = 0; nf < 4; nf++){
      int ocol = cb + wn*64 + nf*16 + fm;
      #pragma unroll
      for (int r = 0; r < 4; r++)
        G[(size_t)(orow + r)*NN + ocol] = acc[mf][nf][r];
    }
  }
}

// ---------------- top-K per row from materialized G (named-register list) ----------------
// R9 lesson: kd[]/ki[] arrays scratch-demote; the top-20 list lives in 40 NAMED
// scalars. Wave per row; lane scans 128 candidates (ascending col order ->
// strict-< insertion is tie-stable); 64-lane (val,idx) pop-merge is exact.
__global__ __launch_bounds__(256)
void k_topk(const float* __restrict__ G, const float* __restrict__ sq,
            int r0, int* __restrict__ idxo){
  __shared__ float lsq[NN];   // 32 KB: sq staged once per block
  int tid = threadIdx.x;
  for (int t = tid; t < NN/4; t += 256)
    ((float4*)lsq)[t] = ((const float4*)sq)[t];
  __syncthreads();

  int wid = tid >> 6, lane = tid & 63;
  int rl = blockIdx.x*4 + wid;
  int gr = r0 + rl;
  const float4* row4 = (const float4*)(G + (size_t)rl*NN);
  const float4* lsq4 = (const float4*)lsq;
  float sqr = lsq[gr];

  float kd0=INFINITY,kd1=INFINITY,kd2=INFINITY,kd3=INFINITY,kd4=INFINITY,
        kd5=INFINITY,kd6=INFINITY,kd7=INFINITY,kd8=INFINITY,kd9=INFINITY,
        kd10=INFINITY,kd11=INFINITY,kd12=INFINITY,kd13=INFINITY,kd14=INFINITY,
        kd15=INFINITY,kd16=INFINITY,kd17=INFINITY,kd18=INFINITY,kd19=INFINITY;
  int ki0=0x7fffffff,ki1=0x7fffffff,ki2=0x7fffffff,ki3=0x7fffffff,ki4=0x7fffffff,
      ki5=0x7fffffff,ki6=0x7fffffff,ki7=0x7fffffff,ki8=0x7fffffff,ki9=0x7fffffff,
      ki10=0x7fffffff,ki11=0x7fffffff,ki12=0x7fffffff,ki13=0x7fffffff,ki14=0x7fffffff,
      ki15=0x7fffffff,ki16=0x7fffffff,ki17=0x7fffffff,ki18=0x7fffffff,ki19=0x7fffffff;

#define ST(U) { bool sw = nk < kd##U; float tv = kd##U; int tq = ki##U; \
      if (sw){ kd##U = nk; ki##U = ni; nk = tv; ni = tq; } }
#define INSE(kc, jc) { if ((kc) < kd19){ float nk = (kc); int ni = (jc); \
      ST(0) ST(1) ST(2) ST(3) ST(4) ST(5) ST(6) ST(7) ST(8) ST(9) \
      ST(10) ST(11) ST(12) ST(13) ST(14) ST(15) ST(16) ST(17) ST(18) ST(19) } }

  #pragma unroll 1
  for (int o = 0; o < 32; o++){
    int t4 = lane + o*64;
    float4 g = row4[t4];
    float4 s = lsq4[t4];
    int jb = t4*4;
    float k0 = (sqr + s.x) - 2.f*g.x;
    float k1 = (sqr + s.y) - 2.f*g.y;
    float k2 = (sqr + s.z) - 2.f*g.z;
    float k3 = (sqr + s.w) - 2.f*g.w;
    float t19 = kd19;
    float mn = fminf(fminf(k0,k1), fminf(k2,k3));
    if (__any(mn < t19)){
      INSE(k0, jb+0);
      INSE(k1, jb+1);
      INSE(k2, jb+2);
      INSE(k3, jb+3);
    }
  }
#undef INSE
#undef ST

  // 64-lane pop-merge: 20 rounds of wave argmin on (val, idx)
#define MV(A,B) { kd##A = kd##B; ki##A = ki##B; }
  #pragma unroll 1
  for (int r = 0; r < KNN; r++){
    float bv = kd0; int bi = ki0;
    #pragma unroll
    for (int mm = 32; mm; mm >>= 1){
      float ov = __shfl_xor(bv, mm); int oi = __shfl_xor(bi, mm);
      if (ov < bv || (ov == bv && oi < bi)){ bv = ov; bi = oi; }
    }
    if (ki0 == bi){   // winner lane (col idx unique per row)
      MV(0,1) MV(1,2) MV(2,3) MV(3,4) MV(4,5) MV(5,6) MV(6,7) MV(7,8) MV(8,9) MV(9,10)
      MV(10,11) MV(11,12) MV(12,13) MV(13,14) MV(14,15) MV(15,16) MV(16,17) MV(17,18) MV(18,19)
      kd19 = INFINITY; ki19 = 0x7fffffff;
    }
    if (lane == 0) idxo[(size_t)gr*KNN + r] = bi;
  }
#undef MV
}

// ---------------- Wd = Wtop - Wbot ----------------
__global__ void k_wd(const float* __restrict__ W, float* __restrict__ Wd, int rows, int M){
  int t = blockIdx.x*256 + threadIdx.x;
  if (t < rows*M) Wd[t] = W[t] - W[rows*M + t];
}

// ---------------- generic tiled matmul: C = A(nxK) @ B(KxM) [+bias][relu] ----------------
__global__ __launch_bounds__(256)
void k_mm(const float* __restrict__ A, const float* __restrict__ B,
          const float* __restrict__ bias, float* __restrict__ Cout,
          int n, int Kd, int M, int relu){
  __shared__ float la[16][68], lb[16][68];
  int tid = threadIdx.x;
  int rb = blockIdx.y*64, cb = blockIdx.x*64;
  int lr = tid >> 2, lq = (tid & 3)*4;
  int ty = tid >> 4, tx = tid & 15;
  float acc[4][4] = {};
  for (int k0 = 0; k0 < Kd; k0 += 16){
    __syncthreads();
    #pragma unroll
    for (int u = 0; u < 4; u++){
      int k = k0 + lq + u;
      la[lq+u][lr] = (k < Kd) ? A[(size_t)(rb+lr)*Kd + k] : 0.f;
    }
    int kk = tid >> 4; int cc = (tid & 15)*4;
    #pragma unroll
    for (int u = 0; u < 4; u++){
      int c = cb + cc + u; int k = k0 + kk;
      lb[kk][cc+u] = (k < Kd && c < M) ? B[(size_t)k*M + c] : 0.f;
    }
    __syncthreads();
    #pragma unroll
    for (int k = 0; k < 16; k++){
      float4 a = *(const float4*)&la[k][ty*4];
      float4 b = *(const float4*)&lb[k][tx*4];
      float avv[4] = {a.x,a.y,a.z,a.w}, bvv[4] = {b.x,b.y,b.z,b.w};
      #pragma unroll
      for (int u = 0; u < 4; u++)
        #pragma unroll
        for (int v = 0; v < 4; v++) acc[u][v] += avv[u]*bvv[v];
    }
  }
  #pragma unroll
  for (int u = 0; u < 4; u++){
    int r = rb + ty*4 + u;
    #pragma unroll
    for (int v = 0; v < 4; v++){
      int c = cb + tx*4 + v;
      if (c < M){
        float x = acc[u][v] + (bias ? bias[c] : 0.f);
        if (relu) x = fmaxf(x, 0.f);
        Cout[(size_t)r*M + c] = x;
      }
    }
  }
}

// ---------------- stats over A[i]+P[j] per channel ----------------
template<int C>
__global__ __launch_bounds__(256)
void k_stats1(const float* __restrict__ A, const float* __restrict__ P,
              const int* __restrict__ idx, float* __restrict__ ssum, float* __restrict__ ssq){
  __shared__ int si[128], sj[128];
  int tid = threadIdx.x;
  int s0 = blockIdx.x*128;
  if (tid < 128){ si[tid] = (s0 + tid)/KNN; sj[tid] = idx[s0 + tid]; }
  __syncthreads();
  constexpr int MPAR = 256/C;
  int tc = tid % C, sr = tid / C;
  float s = 0.f, q = 0.f;
  for (int m = sr; m < 128; m += MPAR){
    float v = A[(size_t)si[m]*C + tc] + P[(size_t)sj[m]*C + tc];
    s += v; q += v*v;
  }
  if constexpr (MPAR > 1){
    __shared__ float rs[256], rq[256];
    rs[tid] = s; rq[tid] = q; __syncthreads();
    if (sr == 0){
      for (int u = 1; u < MPAR; u++){ s += rs[u*C + tc]; q += rq[u*C + tc]; }
    }
  }
  if (sr == 0){ atomicAdd(&ssum[tc], s); atomicAdd(&ssq[tc], q); }
}

// ---------------- column stats over dense X (rows = N*KNN) ----------------
template<int C>
__global__ __launch_bounds__(256)
void k_colstats(const float* __restrict__ X, float* __restrict__ ssum, float* __restrict__ ssq){
  constexpr int MPAR = 256/C;
  int tid = threadIdx.x;
  int tc = tid % C, sr = tid / C;
  int base = blockIdx.x*256;
  float s = 0.f, q = 0.f;
  for (int m = sr; m < 256; m += MPAR){
    float v = X[(size_t)(base + m)*C + tc];
    s += v; q += v*v;
  }
  if constexpr (MPAR > 1){
    __shared__ float rs[256], rq[256];
    rs[tid] = s; rq[tid] = q; __syncthreads();
    if (sr == 0){
      for (int u = 1; u < MPAR; u++){ s += rs[u*C + tc]; q += rq[u*C + tc]; }
    }
  }
  if (sr == 0){ atomicAdd(&ssum[tc], s); atomicAdd(&ssq[tc], q); }
}

__global__ void k_bn_final(const float* __restrict__ ssum, const float* __restrict__ ssq,
                           const float* __restrict__ g, const float* __restrict__ be,
                           float* __restrict__ sb, float* __restrict__ tb, int C, float invn){
  int c = threadIdx.x;
  if (c < C){
    float mu = ssum[c]*invn;
    float var = fmaxf(ssq[c]*invn - mu*mu, 0.f);
    float s = g[c]*rsqrtf(var + 1e-5f);
    sb[c] = s; tb[c] = be[c] - mu*s;
  }
}

// ---------------- per-edge matmul: out = relu(bn1(A[i]+P[j])) @ W + bias ----------------
template<int C>
__global__ __launch_bounds__(256)
void k_edge_mm(const float* __restrict__ A, const float* __restrict__ P,
               const int* __restrict__ idx, const float* __restrict__ sb,
               const float* __restrict__ tb, const float* __restrict__ W,
               const float* __restrict__ bias, float* __restrict__ out){
  constexpr int BM   = (C == 256) ? 32 : 64;
  constexpr int KT   = (C == 256) ? 16 : 64;
  constexpr int COLG = C/8;
  constexpr int ROWG = 256/COLG;
  constexpr int EPT  = BM/ROWG;
  constexpr int MPAR = 256/C;
  __shared__ float e2[BM][C+1];
  __shared__ float wt[KT][C+4];
  __shared__ int sj[BM];
  int tid = threadIdx.x;
  int s0 = blockIdx.x*BM;
  if (tid < BM) sj[tid] = idx[s0 + tid];
  __syncthreads();
  for (int mb = 0; mb < BM; mb += MPAR){
    int m = mb + tid / C;
    int c = tid % C;
    int i = (s0 + m)/KNN;
    int j = sj[m];
    float v = (A[(size_t)i*C + c] + P[(size_t)j*C + c])*sb[c] + tb[c];
    e2[m][c] = fmaxf(v, 0.f);
  }
  float acc[EPT][8];
  #pragma unroll
  for (int m = 0; m < EPT; m++)
    #pragma unroll
    for (int u = 0; u < 8; u++) acc[m][u] = 0.f;
  int tr = tid / COLG, tc = tid % COLG;
  for (int kt = 0; kt < C; kt += KT){
    __syncthreads();
    for (int t = tid; t < KT*C; t += 256){
      wt[t / C][t % C] = W[(size_t)(kt + t/C)*C + (t % C)];
    }
    __syncthreads();
    #pragma unroll 4
    for (int k = 0; k < KT; k++){
      float4 w0 = *(const float4*)&wt[k][tc*8];
      float4 w1 = *(const float4*)&wt[k][tc*8 + 4];
      float b[8] = {w0.x,w0.y,w0.z,w0.w,w1.x,w1.y,w1.z,w1.w};
      #pragma unroll
      for (int m = 0; m < EPT; m++){
        float a = e2[tr*EPT + m][kt + k];
        #pragma unroll
        for (int u = 0; u < 8; u++) acc[m][u] += a*b[u];
      }
    }
  }
  #pragma unroll
  for (int m = 0; m < EPT; m++){
    int row = s0 + tr*EPT + m;
    float4 o0, o1;
    o0.x = acc[m][0] + bias[tc*8+0]; o0.y = acc[m][1] + bias[tc*8+1];
    o0.z = acc[m][2] + bias[tc*8+2]; o0.w = acc[m][3] + bias[tc*8+3];
    o1.x = acc[m][4] + bias[tc*8+4]; o1.y = acc[m][5] + bias[tc*8+5];
    o1.z = acc[m][6] + bias[tc*8+6]; o1.w = acc[m][7] + bias[tc*8+7];
    *(float4*)&out[(size_t)row*C + tc*8]     = o0;
    *(float4*)&out[(size_t)row*C + tc*8 + 4] = o1;
  }
}

// ---------------- bn2 + relu + max over K ----------------
template<int C>
__global__ void k_maxpool(const float* __restrict__ X, const float* __restrict__ sb,
                          const float* __restrict__ tb, float* __restrict__ H){
  constexpr int NPB = 256/C;
  int node = blockIdx.x*NPB + threadIdx.x / C;
  int c = threadIdx.x % C;
  float s = sb[c], t = tb[c];
  float mx = 0.f;
  for (int k = 0; k < KNN; k++){
    float v = X[(size_t)(node*KNN + k)*C + c]*s + t;
    mx = fmaxf(mx, v);
  }
  H[(size_t)node*C + c] = mx;
}

// ---------------- gconv aggregation ----------------
template<int C>
__global__ void k_agg(const float* __restrict__ X, const int* __restrict__ roff,
                      const int* __restrict__ csr, const float* __restrict__ dout,
                      const float* __restrict__ din, float* __restrict__ XA){
  int i = blockIdx.x; int c = threadIdx.x;
  float acc = 0.f;
  int b = roff[i], e = roff[i+1];
  for (int t = b; t < e; t++){
    int s = csr[t];
    acc += X[(size_t)s*C + c]*dout[s];
  }
  XA[(size_t)i*C + c] = acc*din[i];
}

// ================= host =================
extern "C" void kernel_launch(void* const* d_in, const int* in_sizes, int n_in,
                              void* d_out, int out_size, void* d_ws, size_t ws_size,
                              hipStream_t stream){
  const float* feat = (const float*)d_in[0];
  const int*   src  = (const int*)d_in[1];
  const int*   dst  = (const int*)d_in[2];
  const float* Wc1  = (const float*)d_in[3];
  const float* bc1  = (const float*)d_in[4];
  const float* Wc2  = (const float*)d_in[5];
  const float* bc2  = (const float*)d_in[6];
  const float* Wc3  = (const float*)d_in[7];
  const float* bc3  = (const float*)d_in[8];
  const float* W11  = (const float*)d_in[9];
  const float* b11  = (const float*)d_in[10];
  const float* g11  = (const float*)d_in[11];
  const float* be11 = (const float*)d_in[12];
  const float* W12  = (const float*)d_in[13];
  const float* b12  = (const float*)d_in[14];
  const float* g12  = (const float*)d_in[15];
  const float* be12 = (const float*)d_in[16];
  const float* W21  = (const float*)d_in[17];
  const float* b21  = (const float*)d_in[18];
  const float* g21  = (const float*)d_in[19];
  const float* be21 = (const float*)d_in[20];
  const float* W22  = (const float*)d_in[21];
  const float* b22  = (const float*)d_in[22];
  const float* g22  = (const float*)d_in[23];
  const float* be22 = (const float*)d_in[24];
  float* out = (float*)d_out;

  char* w = (char*)d_ws; size_t off = 0;
  auto alloc = [&](size_t bytes)->void*{
    void* p = w + off;
    off += bytes; off = (off + 255) & ~(size_t)255;
    return p;
  };
  int* cnt_s  = (int*)alloc(NN*4);
  int* cnt_d  = (int*)alloc(NN*4);
  int* roff   = (int*)alloc((NN+1)*4);
  int* cursor = (int*)alloc(NN*4);
  int* csr    = (int*)alloc(NE*4);
  int* idx    = (int*)alloc((size_t)NN*KNN*4);
  float* dout = (float*)alloc(NN*4);
  float* din  = (float*)alloc(NN*4);
  float* sqv  = (float*)alloc(NN*4);
  float* h1   = (float*)alloc((size_t)NN*256*4);
  float* h2   = (float*)alloc((size_t)NN*256*4);
  float* h3   = (float*)alloc((size_t)NN*256*4);
  float* h4   = (float*)alloc((size_t)NN*64*4);
  float* xa   = (float*)alloc((size_t)NN*256*4);
  float* Abuf = (float*)alloc((size_t)NN*256*4);
  float* Pbuf = (float*)alloc((size_t)NN*256*4);
  float* Wd   = (float*)alloc(256*256*4);
  float* ssum = (float*)alloc(256*4);
  float* ssq  = (float*)alloc(256*4);
  float* sbn  = (float*)alloc(256*4);
  float* tbn  = (float*)alloc(256*4);
  float* out2 = (float*)alloc((size_t)NN*KNN*256*4);   // 167.8 MB
  // kNN scratch aliases out2 (consumed before edge_mm writes out2):
  float* gram = out2;                                        // CH*NN*4 = 134.2 MB
  unsigned short* xcat = (unsigned short*)(out2 + (size_t)CH*NN);  // 8.4 MB
  (void)ws_size; (void)n_in; (void)in_sizes; (void)out_size;

  const float invn = 1.0f / (float)(NN*KNN);

  // graph prep
  k_zero_i<<<32, 256, 0, stream>>>(cnt_s, NN);
  k_zero_i<<<32, 256, 0, stream>>>(cnt_d, NN);
  k_zero_i<<<32, 256, 0, stream>>>(cursor, NN);
  k_count<<<NE/256, 256, 0, stream>>>(src, dst, cnt_s, cnt_d);
  k_deg<<<32, 256, 0, stream>>>(cnt_s, cnt_d, dout, din);
  k_scan<<<1, 256, 0, stream>>>(cnt_d, roff);
  k_fill<<<NE/256, 256, 0, stream>>>(src, dst, roff, cursor, csr);

  // gconv1 -> h1
  k_gconv1<<<NN/4, 256, 0, stream>>>(feat, roff, csr, dout, din, Wc1, bc1, h1);

  // ---- edge conv 1 (input h1, 256 -> 256 -> 256) ----
  k_sq<<<NN/4, 256, 0, stream>>>(h1, sqv);
  k_split<<<NN, 256, 0, stream>>>(h1, xcat);
  for (int r0 = 0; r0 < NN; r0 += CH){
    k_gram_mfma<<<dim3(NN/GBN, CH/GBM), 256, 0, stream>>>(xcat, gram, r0);
    k_topk<<<CH/4, 256, 0, stream>>>(gram, sqv, r0, idx);
  }
  k_wd<<<256, 256, 0, stream>>>(W11, Wd, 256, 256);
  k_mm<<<dim3(4, NN/64), 256, 0, stream>>>(h1, Wd, b11, Abuf, NN, 256, 256, 0);
  k_mm<<<dim3(4, NN/64), 256, 0, stream>>>(h1, W11 + 256*256, nullptr, Pbuf, NN, 256, 256, 0);
  k_zero<<<2, 256, 0, stream>>>(ssum, 256); k_zero<<<2, 256, 0, stream>>>(ssq, 256);
  k_stats1<256><<<NN*KNN/128, 256, 0, stream>>>(Abuf, Pbuf, idx, ssum, ssq);
  k_bn_final<<<1, 256, 0, stream>>>(ssum, ssq, g11, be11, sbn, tbn, 256, invn);
  k_edge_mm<256><<<NN*KNN/32, 256, 0, stream>>>(Abuf, Pbuf, idx, sbn, tbn, W12, b12, out2);
  k_zero<<<2, 256, 0, stream>>>(ssum, 256); k_zero<<<2, 256, 0, stream>>>(ssq, 256);
  k_colstats<256><<<NN*KNN/256, 256, 0, stream>>>(out2, ssum, ssq);
  k_bn_final<<<1, 256, 0, stream>>>(ssum, ssq, g12, be12, sbn, tbn, 256, invn);
  k_maxpool<256><<<NN, 256, 0, stream>>>(out2, sbn, tbn, h2);

  // gconv2 -> h3
  k_agg<256><<<NN, 256, 0, stream>>>(h2, roff, csr, dout, din, xa);
  k_mm<<<dim3(4, NN/64), 256, 0, stream>>>(xa, Wc2, bc2, h3, NN, 256, 256, 1);

  // ---- edge conv 2 (input h3, 256 -> 64 -> 64) ----
  k_sq<<<NN/4, 256, 0, stream>>>(h3, sqv);
  k_split<<<NN, 256, 0, stream>>>(h3, xcat);
  for (int r0 = 0; r0 < NN; r0 += CH){
    k_gram_mfma<<<dim3(NN/GBN, CH/GBM), 256, 0, stream>>>(xcat, gram, r0);
    k_topk<<<CH/4, 256, 0, stream>>>(gram, sqv, r0, idx);
  }
  k_wd<<<64, 256, 0, stream>>>(W21, Wd, 256, 64);
  k_mm<<<dim3(1, NN/64), 256, 0, stream>>>(h3, Wd, b21, Abuf, NN, 256, 64, 0);
  k_mm<<<dim3(1, NN/64), 256, 0, stream>>>(h3, W21 + 256*64, nullptr, Pbuf, NN, 256, 64, 0);
  k_zero<<<2, 256, 0, stream>>>(ssum, 256); k_zero<<<2, 256, 0, stream>>>(ssq, 256);
  k_stats1<64><<<NN*KNN/128, 256, 0, stream>>>(Abuf, Pbuf, idx, ssum, ssq);
  k_bn_final<<<1, 256, 0, stream>>>(ssum, ssq, g21, be21, sbn, tbn, 64, invn);
  k_edge_mm<64><<<NN*KNN/64, 256, 0, stream>>>(Abuf, Pbuf, idx, sbn, tbn, W22, b22, out2);
  k_zero<<<2, 256, 0, stream>>>(ssum, 256); k_zero<<<2, 256, 0, stream>>>(ssq, 256);
  k_colstats<64><<<NN*KNN/256, 256, 0, stream>>>(out2, ssum, ssq);
  k_bn_final<<<1, 256, 0, stream>>>(ssum, ssq, g22, be22, sbn, tbn, 64, invn);
  k_maxpool<64><<<NN/4, 256, 0, stream>>>(out2, sbn, tbn, h4);

  // gconv3 -> out
  k_agg<64><<<NN, 64, 0, stream>>>(h4, roff, csr, dout, din, xa);
  k_mm<<<dim3(1, NN/64), 256, 0, stream>>>(xa, Wc3, bc3, out, NN, 64, 32, 0);
}

// Round 11
// 1461.571 us; speedup vs baseline: 3.4194x; 1.0973x over previous
//
#include <hip/hip_runtime.h>

#define NN 8192
#define NE 131072
#define KNN 20
#define CH 4096   // gram chunk rows
#define GBM 128
#define GBN 128
#define GBK 64

typedef __attribute__((ext_vector_type(4))) float f32x4;
typedef __attribute__((ext_vector_type(8))) __bf16 bf16x8;

// ---------------- utility ----------------
__global__ void k_zero(float* p, int n){
  int i = blockIdx.x*256 + threadIdx.x;
  if (i < n) p[i] = 0.f;
}
__global__ void k_zero_i(int* p, int n){
  int i = blockIdx.x*256 + threadIdx.x;
  if (i < n) p[i] = 0;
}

__device__ __forceinline__ unsigned short f2bf(float x){
  unsigned u = __float_as_uint(x);
  unsigned r = (u + 0x7fff + ((u >> 16) & 1)) >> 16;
  return (unsigned short)r;
}
__device__ __forceinline__ float bf2f(unsigned short h){
  return __uint_as_float((unsigned)h << 16);
}
__device__ __forceinline__ void gload16(const void* g, void* l){
  __builtin_amdgcn_global_load_lds(
      (const __attribute__((address_space(1))) void*)g,
      (__attribute__((address_space(3))) void*)l, 16, 0, 0);
}

// ---------------- graph prep ----------------
__global__ void k_count(const int* __restrict__ src, const int* __restrict__ dst,
                        int* cs, int* cd){
  int e = blockIdx.x*256 + threadIdx.x;
  if (e < NE){ atomicAdd(&cs[src[e]], 1); atomicAdd(&cd[dst[e]], 1); }
}
__global__ void k_deg(const int* cs, const int* cd, float* dout, float* din){
  int i = blockIdx.x*256 + threadIdx.x;
  if (i < NN){
    dout[i] = rsqrtf((float)max(cs[i], 1));
    din[i]  = rsqrtf((float)max(cd[i], 1));
  }
}
__global__ void k_scan(const int* __restrict__ cnt, int* __restrict__ off){
  __shared__ int sh[256];
  __shared__ int carry;
  int tid = threadIdx.x;
  if (tid == 0) carry = 0;
  __syncthreads();
  for (int base = 0; base < NN; base += 256){
    int v = cnt[base + tid];
    int x = v;
    sh[tid] = x; __syncthreads();
    for (int o = 1; o < 256; o <<= 1){
      int y = (tid >= o) ? sh[tid - o] : 0;
      __syncthreads();
      x += y; sh[tid] = x;
      __syncthreads();
    }
    off[base + tid] = carry + x - v;
    __syncthreads();
    if (tid == 255){
      carry += x;
      if (base + 256 == NN) off[NN] = carry;
    }
    __syncthreads();
  }
}
__global__ void k_fill(const int* __restrict__ src, const int* __restrict__ dst,
                       const int* __restrict__ roff, int* cursor, int* csr){
  int e = blockIdx.x*256 + threadIdx.x;
  if (e < NE){
    int d = dst[e];
    int p = atomicAdd(&cursor[d], 1);
    csr[roff[d] + p] = src[e];
  }
}

// ---------------- gconv1 fused (3 -> 256) ----------------
__global__ void k_gconv1(const float* __restrict__ feat, const int* __restrict__ roff,
                         const int* __restrict__ csr, const float* __restrict__ dout,
                         const float* __restrict__ din, const float* __restrict__ Wc1,
                         const float* __restrict__ bc1, float* __restrict__ h1){
  int wid = threadIdx.x >> 6, lane = threadIdx.x & 63;
  int i = blockIdx.x*4 + wid;
  float a0=0.f, a1=0.f, a2=0.f;
  int beg = roff[i], end = roff[i+1];
  for (int t = beg + lane; t < end; t += 64){
    int s = csr[t]; float w = dout[s];
    a0 += feat[s*3+0]*w; a1 += feat[s*3+1]*w; a2 += feat[s*3+2]*w;
  }
  for (int m = 32; m; m >>= 1){
    a0 += __shfl_xor(a0, m); a1 += __shfl_xor(a1, m); a2 += __shfl_xor(a2, m);
  }
  float dn = din[i];
  a0 *= dn; a1 *= dn; a2 *= dn;
  for (int c = lane; c < 256; c += 64){
    float r = a0*Wc1[c] + a1*Wc1[256+c] + a2*Wc1[512+c] + bc1[c];
    h1[(size_t)i*256 + c] = fmaxf(r, 0.f);
  }
}

// ---------------- row squared norms (C=256) ----------------
__global__ void k_sq(const float* __restrict__ X, float* __restrict__ sq){
  int wid = threadIdx.x >> 6, lane = threadIdx.x & 63;
  int i = blockIdx.x*4 + wid;
  float4 v = *(const float4*)&X[(size_t)i*256 + lane*4];
  float s = v.x*v.x + v.y*v.y + v.z*v.z + v.w*v.w;
  for (int m = 32; m; m >>= 1) s += __shfl_xor(s, m);
  if (lane == 0) sq[i] = s;
}

// ---------------- split f32 -> [hi|lo] bf16, Xcat[n][512] ----------------
__global__ void k_split(const float* __restrict__ X, unsigned short* __restrict__ xcat){
  int row = blockIdx.x, c = threadIdx.x;
  float x = X[(size_t)row*256 + c];
  unsigned short h = f2bf(x);
  unsigned short lo = f2bf(x - bf2f(h));
  xcat[(size_t)row*512 + c] = h;
  xcat[(size_t)row*512 + 256 + c] = lo;
}

// ---------------- W split: Wt_hi/lo[n][k] = split(W[k][n]) (transposed, k-contig) ----------------
__global__ void k_wsplit(const float* __restrict__ W, unsigned short* __restrict__ Whi,
                         unsigned short* __restrict__ Wlo){
  int k = blockIdx.x, n = threadIdx.x;
  float x = W[(size_t)k*256 + n];
  unsigned short h = f2bf(x);
  Whi[(size_t)n*256 + k] = h;
  Wlo[(size_t)n*256 + k] = f2bf(x - bf2f(h));
}

// ---------------- MFMA gram: G[chunk row][j] = x_i . x_j (split bf16, K=768) ----------------
// A sections: {hi, lo, hi}; B sections: {hi, hi, lo}  (R2-verified kernel)
__global__ __launch_bounds__(256)
void k_gram_mfma(const unsigned short* __restrict__ Xcat,
                 float* __restrict__ G, int r0){
  __shared__ unsigned short sA[GBM*GBK];  // 16 KB, swizzled granules
  __shared__ unsigned short sB[GBM*GBK];
  int tid = threadIdx.x;
  int lw = tid >> 6, l = tid & 63;
  int rbl = blockIdx.y*GBM;      // local chunk row base
  int rb = r0 + rbl;             // global source row base (A)
  int cb = blockIdx.x*GBN;       // global source row base (B) = G column base

  int srow = l >> 3;             // 0..7
  int scol = (l & 7) ^ srow;     // swizzled source granule (row&7 == srow)
  const unsigned short* srcA[4];
  const unsigned short* srcB[4];
  char* dstA[4]; char* dstB[4];
  #pragma unroll
  for (int i = 0; i < 4; i++){
    int c = lw*4 + i;
    int row = c*8 + srow;
    srcA[i] = Xcat + (size_t)(rb + row)*512 + scol*8;
    srcB[i] = Xcat + (size_t)(cb + row)*512 + scol*8;
    dstA[i] = (char*)sA + c*1024;
    dstB[i] = (char*)sB + c*1024;
  }

  int wm = lw >> 1, wn = lw & 1;
  int fm = l & 15, kg = l >> 4;
  unsigned offA[4][2], offB[4][2];
  #pragma unroll
  for (int mf = 0; mf < 4; mf++){
    int rowa = wm*64 + mf*16 + fm;
    int rowb = wn*64 + mf*16 + fm;
    #pragma unroll
    for (int ks = 0; ks < 2; ks++){
      offA[mf][ks] = rowa*128 + (((unsigned)(ks*4 + kg) ^ (rowa & 7)))*16;
      offB[mf][ks] = rowb*128 + (((unsigned)(ks*4 + kg) ^ (rowb & 7)))*16;
    }
  }

  f32x4 acc[4][4];
  #pragma unroll
  for (int m = 0; m < 4; m++)
    #pragma unroll
    for (int n = 0; n < 4; n++) acc[m][n] = (f32x4){0.f,0.f,0.f,0.f};

  #pragma unroll
  for (int s = 0; s < 12; s++){
    int sec = s >> 2;
    int inner = (s & 3)*64;
    int cbA = (sec == 1 ? 256 : 0) + inner;
    int cbB = (sec == 2 ? 256 : 0) + inner;
    #pragma unroll
    for (int i = 0; i < 4; i++){
      gload16(srcA[i] + cbA, dstA[i]);
      gload16(srcB[i] + cbB, dstB[i]);
    }
    __syncthreads();
    #pragma unroll
    for (int ks = 0; ks < 2; ks++){
      bf16x8 a[4], b[4];
      #pragma unroll
      for (int mf = 0; mf < 4; mf++) a[mf] = *(const bf16x8*)((const char*)sA + offA[mf][ks]);
      #pragma unroll
      for (int nf = 0; nf < 4; nf++) b[nf] = *(const bf16x8*)((const char*)sB + offB[nf][ks]);
      #pragma unroll
      for (int mf = 0; mf < 4; mf++)
        #pragma unroll
        for (int nf = 0; nf < 4; nf++)
          acc[mf][nf] = __builtin_amdgcn_mfma_f32_16x16x32_bf16(a[mf], b[nf], acc[mf][nf], 0, 0, 0);
    }
    __syncthreads();
  }

  #pragma unroll
  for (int mf = 0; mf < 4; mf++){
    int orow = rbl + wm*64 + mf*16 + kg*4;
    #pragma unroll
    for (int nf = 0; nf < 4; nf++){
      int ocol = cb + wn*64 + nf*16 + fm;
      #pragma unroll
      for (int r = 0; r < 4; r++)
        G[(size_t)(orow + r)*NN + ocol] = acc[mf][nf][r];
    }
  }
}

// ---------------- top-K per row from materialized G (named-register list) ----------------
__global__ __launch_bounds__(256)
void k_topk(const float* __restrict__ G, const float* __restrict__ sq,
            int r0, int* __restrict__ idxo){
  __shared__ float lsq[NN];   // 32 KB: sq staged once per block
  int tid = threadIdx.x;
  for (int t = tid; t < NN/4; t += 256)
    ((float4*)lsq)[t] = ((const float4*)sq)[t];
  __syncthreads();

  int wid = tid >> 6, lane = tid & 63;
  int rl = blockIdx.x*4 + wid;
  int gr = r0 + rl;
  const float4* row4 = (const float4*)(G + (size_t)rl*NN);
  const float4* lsq4 = (const float4*)lsq;
  float sqr = lsq[gr];

  float kd0=INFINITY,kd1=INFINITY,kd2=INFINITY,kd3=INFINITY,kd4=INFINITY,
        kd5=INFINITY,kd6=INFINITY,kd7=INFINITY,kd8=INFINITY,kd9=INFINITY,
        kd10=INFINITY,kd11=INFINITY,kd12=INFINITY,kd13=INFINITY,kd14=INFINITY,
        kd15=INFINITY,kd16=INFINITY,kd17=INFINITY,kd18=INFINITY,kd19=INFINITY;
  int ki0=0x7fffffff,ki1=0x7fffffff,ki2=0x7fffffff,ki3=0x7fffffff,ki4=0x7fffffff,
      ki5=0x7fffffff,ki6=0x7fffffff,ki7=0x7fffffff,ki8=0x7fffffff,ki9=0x7fffffff,
      ki10=0x7fffffff,ki11=0x7fffffff,ki12=0x7fffffff,ki13=0x7fffffff,ki14=0x7fffffff,
      ki15=0x7fffffff,ki16=0x7fffffff,ki17=0x7fffffff,ki18=0x7fffffff,ki19=0x7fffffff;

#define ST(U) { bool sw = nk < kd##U; float tv = kd##U; int tq = ki##U; \
      if (sw){ kd##U = nk; ki##U = ni; nk = tv; ni = tq; } }
#define INSE(kc, jc) { if ((kc) < kd19){ float nk = (kc); int ni = (jc); \
      ST(0) ST(1) ST(2) ST(3) ST(4) ST(5) ST(6) ST(7) ST(8) ST(9) \
      ST(10) ST(11) ST(12) ST(13) ST(14) ST(15) ST(16) ST(17) ST(18) ST(19) } }

  #pragma unroll 1
  for (int o = 0; o < 32; o++){
    int t4 = lane + o*64;
    float4 g = row4[t4];
    float4 s = lsq4[t4];
    int jb = t4*4;
    float k0 = (sqr + s.x) - 2.f*g.x;
    float k1 = (sqr + s.y) - 2.f*g.y;
    float k2 = (sqr + s.z) - 2.f*g.z;
    float k3 = (sqr + s.w) - 2.f*g.w;
    float t19 = kd19;
    float mn = fminf(fminf(k0,k1), fminf(k2,k3));
    if (__any(mn < t19)){
      INSE(k0, jb+0);
      INSE(k1, jb+1);
      INSE(k2, jb+2);
      INSE(k3, jb+3);
    }
  }
#undef INSE
#undef ST

#define MV(A,B) { kd##A = kd##B; ki##A = ki##B; }
  #pragma unroll 1
  for (int r = 0; r < KNN; r++){
    float bv = kd0; int bi = ki0;
    #pragma unroll
    for (int mm = 32; mm; mm >>= 1){
      float ov = __shfl_xor(bv, mm); int oi = __shfl_xor(bi, mm);
      if (ov < bv || (ov == bv && oi < bi)){ bv = ov; bi = oi; }
    }
    if (ki0 == bi){
      MV(0,1) MV(1,2) MV(2,3) MV(3,4) MV(4,5) MV(5,6) MV(6,7) MV(7,8) MV(8,9) MV(9,10)
      MV(10,11) MV(11,12) MV(12,13) MV(13,14) MV(14,15) MV(15,16) MV(16,17) MV(17,18) MV(18,19)
      kd19 = INFINITY; ki19 = 0x7fffffff;
    }
    if (lane == 0) idxo[(size_t)gr*KNN + r] = bi;
  }
#undef MV
}

// ---------------- Wd = Wtop - Wbot ----------------
__global__ void k_wd(const float* __restrict__ W, float* __restrict__ Wd, int rows, int M){
  int t = blockIdx.x*256 + threadIdx.x;
  if (t < rows*M) Wd[t] = W[t] - W[rows*M + t];
}

// ---------------- generic tiled matmul: C = A(nxK) @ B(KxM) [+bias][relu] ----------------
__global__ __launch_bounds__(256)
void k_mm(const float* __restrict__ A, const float* __restrict__ B,
          const float* __restrict__ bias, float* __restrict__ Cout,
          int n, int Kd, int M, int relu){
  __shared__ float la[16][68], lb[16][68];
  int tid = threadIdx.x;
  int rb = blockIdx.y*64, cb = blockIdx.x*64;
  int lr = tid >> 2, lq = (tid & 3)*4;
  int ty = tid >> 4, tx = tid & 15;
  float acc[4][4] = {};
  for (int k0 = 0; k0 < Kd; k0 += 16){
    __syncthreads();
    #pragma unroll
    for (int u = 0; u < 4; u++){
      int k = k0 + lq + u;
      la[lq+u][lr] = (k < Kd) ? A[(size_t)(rb+lr)*Kd + k] : 0.f;
    }
    int kk = tid >> 4; int cc = (tid & 15)*4;
    #pragma unroll
    for (int u = 0; u < 4; u++){
      int c = cb + cc + u; int k = k0 + kk;
      lb[kk][cc+u] = (k < Kd && c < M) ? B[(size_t)k*M + c] : 0.f;
    }
    __syncthreads();
    #pragma unroll
    for (int k = 0; k < 16; k++){
      float4 a = *(const float4*)&la[k][ty*4];
      float4 b = *(const float4*)&lb[k][tx*4];
      float avv[4] = {a.x,a.y,a.z,a.w}, bvv[4] = {b.x,b.y,b.z,b.w};
      #pragma unroll
      for (int u = 0; u < 4; u++)
        #pragma unroll
        for (int v = 0; v < 4; v++) acc[u][v] += avv[u]*bvv[v];
    }
  }
  #pragma unroll
  for (int u = 0; u < 4; u++){
    int r = rb + ty*4 + u;
    #pragma unroll
    for (int v = 0; v < 4; v++){
      int c = cb + tx*4 + v;
      if (c < M){
        float x = acc[u][v] + (bias ? bias[c] : 0.f);
        if (relu) x = fmaxf(x, 0.f);
        Cout[(size_t)r*M + c] = x;
      }
    }
  }
}

// ---------------- stats over A[i]+P[j] per channel ----------------
template<int C>
__global__ __launch_bounds__(256)
void k_stats1(const float* __restrict__ A, const float* __restrict__ P,
              const int* __restrict__ idx, float* __restrict__ ssum, float* __restrict__ ssq){
  __shared__ int si[128], sj[128];
  int tid = threadIdx.x;
  int s0 = blockIdx.x*128;
  if (tid < 128){ si[tid] = (s0 + tid)/KNN; sj[tid] = idx[s0 + tid]; }
  __syncthreads();
  constexpr int MPAR = 256/C;
  int tc = tid % C, sr = tid / C;
  float s = 0.f, q = 0.f;
  for (int m = sr; m < 128; m += MPAR){
    float v = A[(size_t)si[m]*C + tc] + P[(size_t)sj[m]*C + tc];
    s += v; q += v*v;
  }
  if constexpr (MPAR > 1){
    __shared__ float rs[256], rq[256];
    rs[tid] = s; rq[tid] = q; __syncthreads();
    if (sr == 0){
      for (int u = 1; u < MPAR; u++){ s += rs[u*C + tc]; q += rq[u*C + tc]; }
    }
  }
  if (sr == 0){ atomicAdd(&ssum[tc], s); atomicAdd(&ssq[tc], q); }
}

// ---------------- column stats over dense X (rows = N*KNN) ----------------
template<int C>
__global__ __launch_bounds__(256)
void k_colstats(const float* __restrict__ X, float* __restrict__ ssum, float* __restrict__ ssq){
  constexpr int MPAR = 256/C;
  int tid = threadIdx.x;
  int tc = tid % C, sr = tid / C;
  int base = blockIdx.x*256;
  float s = 0.f, q = 0.f;
  for (int m = sr; m < 256; m += MPAR){
    float v = X[(size_t)(base + m)*C + tc];
    s += v; q += v*v;
  }
  if constexpr (MPAR > 1){
    __shared__ float rs[256], rq[256];
    rs[tid] = s; rq[tid] = q; __syncthreads();
    if (sr == 0){
      for (int u = 1; u < MPAR; u++){ s += rs[u*C + tc]; q += rq[u*C + tc]; }
    }
  }
  if (sr == 0){ atomicAdd(&ssum[tc], s); atomicAdd(&ssq[tc], q); }
}

__global__ void k_bn_final(const float* __restrict__ ssum, const float* __restrict__ ssq,
                           const float* __restrict__ g, const float* __restrict__ be,
                           float* __restrict__ sb, float* __restrict__ tb, int C, float invn){
  int c = threadIdx.x;
  if (c < C){
    float mu = ssum[c]*invn;
    float var = fmaxf(ssq[c]*invn - mu*mu, 0.f);
    float s = g[c]*rsqrtf(var + 1e-5f);
    sb[c] = s; tb[c] = be[c] - mu*s;
  }
}

// ---------------- MFMA per-edge matmul (C=256): out = relu(bn1(A[i]+P[j])) @ W + bias ----
// Split-bf16 (hi/lo) like the gram kernel: out = Ehi@Whi + Elo@Whi + Ehi@Wlo.
// Block = 64 edges x 256 out-channels; 4 waves, each 64x64. E staged in LDS with
// XOR-granule swizzle (g ^= row&7, bijective, both sides consistent); W read
// directly from global (transposed split Wt[n][k], 256 KB, L2-resident).
__global__ __launch_bounds__(256, 2)
void k_edge_mfma(const float* __restrict__ A, const float* __restrict__ P,
                 const int* __restrict__ idx, const float* __restrict__ sb,
                 const float* __restrict__ tb, const unsigned short* __restrict__ Wthi,
                 const unsigned short* __restrict__ Wtlo, const float* __restrict__ bias,
                 float* __restrict__ out){
  __shared__ unsigned short ehi[64*256];   // 32 KB
  __shared__ unsigned short elo[64*256];   // 32 KB
  __shared__ int sj[64];
  int tid = threadIdx.x;
  int lw = tid >> 6, l = tid & 63;
  int s0 = blockIdx.x*64;
  if (tid < 64) sj[tid] = idx[s0 + tid];
  float sbc = sb[tid], tbc = tb[tid];
  __syncthreads();

  // prep: iteration it = edge row, col = tid
  #pragma unroll 1
  for (int it = 0; it < 64; it++){
    int i = (s0 + it)/KNN;          // uniform
    int j = sj[it];                 // uniform
    float v = (A[(size_t)i*256 + tid] + P[(size_t)j*256 + tid])*sbc + tbc;
    v = fmaxf(v, 0.f);
    unsigned short h = f2bf(v);
    unsigned short lo = f2bf(v - bf2f(h));
    unsigned off = (unsigned)it*512 + (((unsigned)tid*2) ^ (((unsigned)it & 7) << 4));
    *(unsigned short*)((char*)ehi + off) = h;
    *(unsigned short*)((char*)elo + off) = lo;
  }
  __syncthreads();

  int fm = l & 15, kg = l >> 4;
  const unsigned short* bhi[4];
  const unsigned short* blo[4];
  float bz[4];
  #pragma unroll
  for (int nf = 0; nf < 4; nf++){
    int col = lw*64 + nf*16 + fm;
    bhi[nf] = Wthi + (size_t)col*256 + kg*8;
    blo[nf] = Wtlo + (size_t)col*256 + kg*8;
    bz[nf] = bias[col];
  }

  f32x4 acc[4][4];
  #pragma unroll
  for (int m = 0; m < 4; m++)
    #pragma unroll
    for (int n = 0; n < 4; n++) acc[m][n] = (f32x4){0.f,0.f,0.f,0.f};

  #pragma unroll 1
  for (int sec = 0; sec < 3; sec++){
    const char* abase = (sec == 1) ? (const char*)elo : (const char*)ehi;
    int bsec = (sec == 2);
    #pragma unroll 1
    for (int st = 0; st < 8; st++){
      int g = st*4 + kg;
      bf16x8 a[4], b[4];
      #pragma unroll
      for (int mf = 0; mf < 4; mf++){
        int row = mf*16 + fm;
        a[mf] = *(const bf16x8*)(abase + row*512 + ((unsigned)(g ^ (row & 7)))*16);
      }
      #pragma unroll
      for (int nf = 0; nf < 4; nf++){
        const unsigned short* bp = bsec ? blo[nf] : bhi[nf];
        b[nf] = *(const bf16x8*)(bp + st*32);
      }
      #pragma unroll
      for (int mf = 0; mf < 4; mf++)
        #pragma unroll
        for (int nf = 0; nf < 4; nf++)
          acc[mf][nf] = __builtin_amdgcn_mfma_f32_16x16x32_bf16(a[mf], b[nf], acc[mf][nf], 0, 0, 0);
    }
  }

  // C/D: col = lane&15, row = (lane>>4)*4 + r
  #pragma unroll
  for (int mf = 0; mf < 4; mf++){
    #pragma unroll
    for (int nf = 0; nf < 4; nf++){
      int col = lw*64 + nf*16 + fm;
      #pragma unroll
      for (int r = 0; r < 4; r++){
        int row = s0 + mf*16 + kg*4 + r;
        out[(size_t)row*256 + col] = acc[mf][nf][r] + bz[nf];
      }
    }
  }
}

// ---------------- per-edge matmul (f32, kept for C=64) ----------------
template<int C>
__global__ __launch_bounds__(256)
void k_edge_mm(const float* __restrict__ A, const float* __restrict__ P,
               const int* __restrict__ idx, const float* __restrict__ sb,
               const float* __restrict__ tb, const float* __restrict__ W,
               const float* __restrict__ bias, float* __restrict__ out){
  constexpr int BM   = (C == 256) ? 32 : 64;
  constexpr int KT   = (C == 256) ? 16 : 64;
  constexpr int COLG = C/8;
  constexpr int ROWG = 256/COLG;
  constexpr int EPT  = BM/ROWG;
  constexpr int MPAR = 256/C;
  __shared__ float e2[BM][C+1];
  __shared__ float wt[KT][C+4];
  __shared__ int sj[BM];
  int tid = threadIdx.x;
  int s0 = blockIdx.x*BM;
  if (tid < BM) sj[tid] = idx[s0 + tid];
  __syncthreads();
  for (int mb = 0; mb < BM; mb += MPAR){
    int m = mb + tid / C;
    int c = tid % C;
    int i = (s0 + m)/KNN;
    int j = sj[m];
    float v = (A[(size_t)i*C + c] + P[(size_t)j*C + c])*sb[c] + tb[c];
    e2[m][c] = fmaxf(v, 0.f);
  }
  float acc[EPT][8];
  #pragma unroll
  for (int m = 0; m < EPT; m++)
    #pragma unroll
    for (int u = 0; u < 8; u++) acc[m][u] = 0.f;
  int tr = tid / COLG, tc = tid % COLG;
  for (int kt = 0; kt < C; kt += KT){
    __syncthreads();
    for (int t = tid; t < KT*C; t += 256){
      wt[t / C][t % C] = W[(size_t)(kt + t/C)*C + (t % C)];
    }
    __syncthreads();
    #pragma unroll 4
    for (int k = 0; k < KT; k++){
      float4 w0 = *(const float4*)&wt[k][tc*8];
      float4 w1 = *(const float4*)&wt[k][tc*8 + 4];
      float b[8] = {w0.x,w0.y,w0.z,w0.w,w1.x,w1.y,w1.z,w1.w};
      #pragma unroll
      for (int m = 0; m < EPT; m++){
        float a = e2[tr*EPT + m][kt + k];
        #pragma unroll
        for (int u = 0; u < 8; u++) acc[m][u] += a*b[u];
      }
    }
  }
  #pragma unroll
  for (int m = 0; m < EPT; m++){
    int row = s0 + tr*EPT + m;
    float4 o0, o1;
    o0.x = acc[m][0] + bias[tc*8+0]; o0.y = acc[m][1] + bias[tc*8+1];
    o0.z = acc[m][2] + bias[tc*8+2]; o0.w = acc[m][3] + bias[tc*8+3];
    o1.x = acc[m][4] + bias[tc*8+4]; o1.y = acc[m][5] + bias[tc*8+5];
    o1.z = acc[m][6] + bias[tc*8+6]; o1.w = acc[m][7] + bias[tc*8+7];
    *(float4*)&out[(size_t)row*C + tc*8]     = o0;
    *(float4*)&out[(size_t)row*C + tc*8 + 4] = o1;
  }
}

// ---------------- bn2 + relu + max over K ----------------
template<int C>
__global__ void k_maxpool(const float* __restrict__ X, const float* __restrict__ sb,
                          const float* __restrict__ tb, float* __restrict__ H){
  constexpr int NPB = 256/C;
  int node = blockIdx.x*NPB + threadIdx.x / C;
  int c = threadIdx.x % C;
  float s = sb[c], t = tb[c];
  float mx = 0.f;
  for (int k = 0; k < KNN; k++){
    float v = X[(size_t)(node*KNN + k)*C + c]*s + t;
    mx = fmaxf(mx, v);
  }
  H[(size_t)node*C + c] = mx;
}

// ---------------- gconv aggregation ----------------
template<int C>
__global__ void k_agg(const float* __restrict__ X, const int* __restrict__ roff,
                      const int* __restrict__ csr, const float* __restrict__ dout,
                      const float* __restrict__ din, float* __restrict__ XA){
  int i = blockIdx.x; int c = threadIdx.x;
  float acc = 0.f;
  int b = roff[i], e = roff[i+1];
  for (int t = b; t < e; t++){
    int s = csr[t];
    acc += X[(size_t)s*C + c]*dout[s];
  }
  XA[(size_t)i*C + c] = acc*din[i];
}

// ================= host =================
extern "C" void kernel_launch(void* const* d_in, const int* in_sizes, int n_in,
                              void* d_out, int out_size, void* d_ws, size_t ws_size,
                              hipStream_t stream){
  const float* feat = (const float*)d_in[0];
  const int*   src  = (const int*)d_in[1];
  const int*   dst  = (const int*)d_in[2];
  const float* Wc1  = (const float*)d_in[3];
  const float* bc1  = (const float*)d_in[4];
  const float* Wc2  = (const float*)d_in[5];
  const float* bc2  = (const float*)d_in[6];
  const float* Wc3  = (const float*)d_in[7];
  const float* bc3  = (const float*)d_in[8];
  const float* W11  = (const float*)d_in[9];
  const float* b11  = (const float*)d_in[10];
  const float* g11  = (const float*)d_in[11];
  const float* be11 = (const float*)d_in[12];
  const float* W12  = (const float*)d_in[13];
  const float* b12  = (const float*)d_in[14];
  const float* g12  = (const float*)d_in[15];
  const float* be12 = (const float*)d_in[16];
  const float* W21  = (const float*)d_in[17];
  const float* b21  = (const float*)d_in[18];
  const float* g21  = (const float*)d_in[19];
  const float* be21 = (const float*)d_in[20];
  const float* W22  = (const float*)d_in[21];
  const float* b22  = (const float*)d_in[22];
  const float* g22  = (const float*)d_in[23];
  const float* be22 = (const float*)d_in[24];
  float* out = (float*)d_out;

  char* w = (char*)d_ws; size_t off = 0;
  auto alloc = [&](size_t bytes)->void*{
    void* p = w + off;
    off += bytes; off = (off + 255) & ~(size_t)255;
    return p;
  };
  int* cnt_s  = (int*)alloc(NN*4);
  int* cnt_d  = (int*)alloc(NN*4);
  int* roff   = (int*)alloc((NN+1)*4);
  int* cursor = (int*)alloc(NN*4);
  int* csr    = (int*)alloc(NE*4);
  int* idx    = (int*)alloc((size_t)NN*KNN*4);
  float* dout = (float*)alloc(NN*4);
  float* din  = (float*)alloc(NN*4);
  float* sqv  = (float*)alloc(NN*4);
  float* h1   = (float*)alloc((size_t)NN*256*4);
  float* h2   = (float*)alloc((size_t)NN*256*4);
  float* h3   = (float*)alloc((size_t)NN*256*4);
  float* h4   = (float*)alloc((size_t)NN*64*4);
  float* xa   = (float*)alloc((size_t)NN*256*4);
  float* Abuf = (float*)alloc((size_t)NN*256*4);
  float* Pbuf = (float*)alloc((size_t)NN*256*4);
  float* Wd   = (float*)alloc(256*256*4);
  float* ssum = (float*)alloc(256*4);
  float* ssq  = (float*)alloc(256*4);
  float* sbn  = (float*)alloc(256*4);
  float* tbn  = (float*)alloc(256*4);
  unsigned short* wthi = (unsigned short*)alloc(256*256*2);
  unsigned short* wtlo = (unsigned short*)alloc(256*256*2);
  float* out2 = (float*)alloc((size_t)NN*KNN*256*4);   // 167.8 MB
  // kNN scratch aliases out2 (consumed before edge_mm writes out2):
  float* gram = out2;                                        // CH*NN*4 = 134.2 MB
  unsigned short* xcat = (unsigned short*)(out2 + (size_t)CH*NN);  // 8.4 MB
  (void)ws_size; (void)n_in; (void)in_sizes; (void)out_size;

  const float invn = 1.0f / (float)(NN*KNN);

  // graph prep
  k_zero_i<<<32, 256, 0, stream>>>(cnt_s, NN);
  k_zero_i<<<32, 256, 0, stream>>>(cnt_d, NN);
  k_zero_i<<<32, 256, 0, stream>>>(cursor, NN);
  k_count<<<NE/256, 256, 0, stream>>>(src, dst, cnt_s, cnt_d);
  k_deg<<<32, 256, 0, stream>>>(cnt_s, cnt_d, dout, din);
  k_scan<<<1, 256, 0, stream>>>(cnt_d, roff);
  k_fill<<<NE/256, 256, 0, stream>>>(src, dst, roff, cursor, csr);

  // gconv1 -> h1
  k_gconv1<<<NN/4, 256, 0, stream>>>(feat, roff, csr, dout, din, Wc1, bc1, h1);

  // ---- edge conv 1 (input h1, 256 -> 256 -> 256) ----
  k_sq<<<NN/4, 256, 0, stream>>>(h1, sqv);
  k_split<<<NN, 256, 0, stream>>>(h1, xcat);
  for (int r0 = 0; r0 < NN; r0 += CH){
    k_gram_mfma<<<dim3(NN/GBN, CH/GBM), 256, 0, stream>>>(xcat, gram, r0);
    k_topk<<<CH/4, 256, 0, stream>>>(gram, sqv, r0, idx);
  }
  k_wd<<<256, 256, 0, stream>>>(W11, Wd, 256, 256);
  k_wsplit<<<256, 256, 0, stream>>>(W12, wthi, wtlo);
  k_mm<<<dim3(4, NN/64), 256, 0, stream>>>(h1, Wd, b11, Abuf, NN, 256, 256, 0);
  k_mm<<<dim3(4, NN/64), 256, 0, stream>>>(h1, W11 + 256*256, nullptr, Pbuf, NN, 256, 256, 0);
  k_zero<<<2, 256, 0, stream>>>(ssum, 256); k_zero<<<2, 256, 0, stream>>>(ssq, 256);
  k_stats1<256><<<NN*KNN/128, 256, 0, stream>>>(Abuf, Pbuf, idx, ssum, ssq);
  k_bn_final<<<1, 256, 0, stream>>>(ssum, ssq, g11, be11, sbn, tbn, 256, invn);
  k_edge_mfma<<<NN*KNN/64, 256, 0, stream>>>(Abuf, Pbuf, idx, sbn, tbn, wthi, wtlo, b12, out2);
  k_zero<<<2, 256, 0, stream>>>(ssum, 256); k_zero<<<2, 256, 0, stream>>>(ssq, 256);
  k_colstats<256><<<NN*KNN/256, 256, 0, stream>>>(out2, ssum, ssq);
  k_bn_final<<<1, 256, 0, stream>>>(ssum, ssq, g12, be12, sbn, tbn, 256, invn);
  k_maxpool<256><<<NN, 256, 0, stream>>>(out2, sbn, tbn, h2);

  // gconv2 -> h3
  k_agg<256><<<NN, 256, 0, stream>>>(h2, roff, csr, dout, din, xa);
  k_mm<<<dim3(4, NN/64), 256, 0, stream>>>(xa, Wc2, bc2, h3, NN, 256, 256, 1);

  // ---- edge conv 2 (input h3, 256 -> 64 -> 64) ----
  k_sq<<<NN/4, 256, 0, stream>>>(h3, sqv);
  k_split<<<NN, 256, 0, stream>>>(h3, xcat);
  for (int r0 = 0; r0 < NN; r0 += CH){
    k_gram_mfma<<<dim3(NN/GBN, CH/GBM), 256, 0, stream>>>(xcat, gram, r0);
    k_topk<<<CH/4, 256, 0, stream>>>(gram, sqv, r0, idx);
  }
  k_wd<<<64, 256, 0, stream>>>(W21, Wd, 256, 64);
  k_mm<<<dim3(1, NN/64), 256, 0, stream>>>(h3, Wd, b21, Abuf, NN, 256, 64, 0);
  k_mm<<<dim3(1, NN/64), 256, 0, stream>>>(h3, W21 + 256*64, nullptr, Pbuf, NN, 256, 64, 0);
  k_zero<<<2, 256, 0, stream>>>(ssum, 256); k_zero<<<2, 256, 0, stream>>>(ssq, 256);
  k_stats1<64><<<NN*KNN/128, 256, 0, stream>>>(Abuf, Pbuf, idx, ssum, ssq);
  k_bn_final<<<1, 256, 0, stream>>>(ssum, ssq, g21, be21, sbn, tbn, 64, invn);
  k_edge_mm<64><<<NN*KNN/64, 256, 0, stream>>>(Abuf, Pbuf, idx, sbn, tbn, W22, b22, out2);
  k_zero<<<2, 256, 0, stream>>>(ssum, 256); k_zero<<<2, 256, 0, stream>>>(ssq, 256);
  k_colstats<64><<<NN*KNN/256, 256, 0, stream>>>(out2, ssum, ssq);
  k_bn_final<<<1, 256, 0, stream>>>(ssum, ssq, g22, be22, sbn, tbn, 64, invn);
  k_maxpool<64><<<NN/4, 256, 0, stream>>>(out2, sbn, tbn, h4);

  // gconv3 -> out
  k_agg<64><<<NN, 64, 0, stream>>>(h4, roff, csr, dout, din, xa);
  k_mm<<<dim3(1, NN/64), 256, 0, stream>>>(xa, Wc3, bc3, out, NN, 64, 32, 0);
}

// Round 12
// 1392.837 us; speedup vs baseline: 3.5881x; 1.0493x over previous
//
#include <hip/hip_runtime.h>

#define NN 8192
#define NE 131072
#define KNN 20
#define CH 4096   // gram chunk rows
#define GBM 128
#define GBN 128
#define GBK 64

typedef __attribute__((ext_vector_type(4))) float f32x4;
typedef __attribute__((ext_vector_type(8))) __bf16 bf16x8;

// ---------------- utility ----------------
__global__ void k_zero(float* p, int n){
  int i = blockIdx.x*256 + threadIdx.x;
  if (i < n) p[i] = 0.f;
}
__global__ void k_zero_i(int* p, int n){
  int i = blockIdx.x*256 + threadIdx.x;
  if (i < n) p[i] = 0;
}

__device__ __forceinline__ unsigned short f2bf(float x){
  unsigned u = __float_as_uint(x);
  unsigned r = (u + 0x7fff + ((u >> 16) & 1)) >> 16;
  return (unsigned short)r;
}
__device__ __forceinline__ float bf2f(unsigned short h){
  return __uint_as_float((unsigned)h << 16);
}
__device__ __forceinline__ void gload16(const void* g, void* l){
  __builtin_amdgcn_global_load_lds(
      (const __attribute__((address_space(1))) void*)g,
      (__attribute__((address_space(3))) void*)l, 16, 0, 0);
}

// ---------------- graph prep ----------------
__global__ void k_count(const int* __restrict__ src, const int* __restrict__ dst,
                        int* cs, int* cd){
  int e = blockIdx.x*256 + threadIdx.x;
  if (e < NE){ atomicAdd(&cs[src[e]], 1); atomicAdd(&cd[dst[e]], 1); }
}
__global__ void k_deg(const int* cs, const int* cd, float* dout, float* din){
  int i = blockIdx.x*256 + threadIdx.x;
  if (i < NN){
    dout[i] = rsqrtf((float)max(cs[i], 1));
    din[i]  = rsqrtf((float)max(cd[i], 1));
  }
}
__global__ void k_scan(const int* __restrict__ cnt, int* __restrict__ off){
  __shared__ int sh[256];
  __shared__ int carry;
  int tid = threadIdx.x;
  if (tid == 0) carry = 0;
  __syncthreads();
  for (int base = 0; base < NN; base += 256){
    int v = cnt[base + tid];
    int x = v;
    sh[tid] = x; __syncthreads();
    for (int o = 1; o < 256; o <<= 1){
      int y = (tid >= o) ? sh[tid - o] : 0;
      __syncthreads();
      x += y; sh[tid] = x;
      __syncthreads();
    }
    off[base + tid] = carry + x - v;
    __syncthreads();
    if (tid == 255){
      carry += x;
      if (base + 256 == NN) off[NN] = carry;
    }
    __syncthreads();
  }
}
__global__ void k_fill(const int* __restrict__ src, const int* __restrict__ dst,
                       const int* __restrict__ roff, int* cursor, int* csr){
  int e = blockIdx.x*256 + threadIdx.x;
  if (e < NE){
    int d = dst[e];
    int p = atomicAdd(&cursor[d], 1);
    csr[roff[d] + p] = src[e];
  }
}

// ---------------- gconv1 fused (3 -> 256) ----------------
__global__ void k_gconv1(const float* __restrict__ feat, const int* __restrict__ roff,
                         const int* __restrict__ csr, const float* __restrict__ dout,
                         const float* __restrict__ din, const float* __restrict__ Wc1,
                         const float* __restrict__ bc1, float* __restrict__ h1){
  int wid = threadIdx.x >> 6, lane = threadIdx.x & 63;
  int i = blockIdx.x*4 + wid;
  float a0=0.f, a1=0.f, a2=0.f;
  int beg = roff[i], end = roff[i+1];
  for (int t = beg + lane; t < end; t += 64){
    int s = csr[t]; float w = dout[s];
    a0 += feat[s*3+0]*w; a1 += feat[s*3+1]*w; a2 += feat[s*3+2]*w;
  }
  for (int m = 32; m; m >>= 1){
    a0 += __shfl_xor(a0, m); a1 += __shfl_xor(a1, m); a2 += __shfl_xor(a2, m);
  }
  float dn = din[i];
  a0 *= dn; a1 *= dn; a2 *= dn;
  for (int c = lane; c < 256; c += 64){
    float r = a0*Wc1[c] + a1*Wc1[256+c] + a2*Wc1[512+c] + bc1[c];
    h1[(size_t)i*256 + c] = fmaxf(r, 0.f);
  }
}

// ---------------- row squared norms (C=256) ----------------
__global__ void k_sq(const float* __restrict__ X, float* __restrict__ sq){
  int wid = threadIdx.x >> 6, lane = threadIdx.x & 63;
  int i = blockIdx.x*4 + wid;
  float4 v = *(const float4*)&X[(size_t)i*256 + lane*4];
  float s = v.x*v.x + v.y*v.y + v.z*v.z + v.w*v.w;
  for (int m = 32; m; m >>= 1) s += __shfl_xor(s, m);
  if (lane == 0) sq[i] = s;
}

// ---------------- split f32 -> [hi|lo] bf16, Xcat[n][512] ----------------
__global__ void k_split(const float* __restrict__ X, unsigned short* __restrict__ xcat){
  int row = blockIdx.x, c = threadIdx.x;
  float x = X[(size_t)row*256 + c];
  unsigned short h = f2bf(x);
  unsigned short lo = f2bf(x - bf2f(h));
  xcat[(size_t)row*512 + c] = h;
  xcat[(size_t)row*512 + 256 + c] = lo;
}

// ---------------- W split: Wt_hi/lo[n][k] = split(W[k][n]) (transposed, k-contig) ----------------
__global__ void k_wsplit(const float* __restrict__ W, unsigned short* __restrict__ Whi,
                         unsigned short* __restrict__ Wlo){
  int k = blockIdx.x, n = threadIdx.x;
  float x = W[(size_t)k*256 + n];
  unsigned short h = f2bf(x);
  Whi[(size_t)n*256 + k] = h;
  Wlo[(size_t)n*256 + k] = f2bf(x - bf2f(h));
}
__global__ void k_wsplit64(const float* __restrict__ W, unsigned short* __restrict__ Whi,
                           unsigned short* __restrict__ Wlo){
  int k = blockIdx.x, n = threadIdx.x;   // 64 x 64
  float x = W[(size_t)k*64 + n];
  unsigned short h = f2bf(x);
  Whi[(size_t)n*64 + k] = h;
  Wlo[(size_t)n*64 + k] = f2bf(x - bf2f(h));
}

// ---------------- MFMA gram: G[chunk row][j] = x_i . x_j (split bf16, K=768) ----------------
// A sections: {hi, lo, hi}; B sections: {hi, hi, lo}  (R2-verified kernel)
__global__ __launch_bounds__(256)
void k_gram_mfma(const unsigned short* __restrict__ Xcat,
                 float* __restrict__ G, int r0){
  __shared__ unsigned short sA[GBM*GBK];  // 16 KB, swizzled granules
  __shared__ unsigned short sB[GBM*GBK];
  int tid = threadIdx.x;
  int lw = tid >> 6, l = tid & 63;
  int rbl = blockIdx.y*GBM;      // local chunk row base
  int rb = r0 + rbl;             // global source row base (A)
  int cb = blockIdx.x*GBN;       // global source row base (B) = G column base

  int srow = l >> 3;             // 0..7
  int scol = (l & 7) ^ srow;     // swizzled source granule (row&7 == srow)
  const unsigned short* srcA[4];
  const unsigned short* srcB[4];
  char* dstA[4]; char* dstB[4];
  #pragma unroll
  for (int i = 0; i < 4; i++){
    int c = lw*4 + i;
    int row = c*8 + srow;
    srcA[i] = Xcat + (size_t)(rb + row)*512 + scol*8;
    srcB[i] = Xcat + (size_t)(cb + row)*512 + scol*8;
    dstA[i] = (char*)sA + c*1024;
    dstB[i] = (char*)sB + c*1024;
  }

  int wm = lw >> 1, wn = lw & 1;
  int fm = l & 15, kg = l >> 4;
  unsigned offA[4][2], offB[4][2];
  #pragma unroll
  for (int mf = 0; mf < 4; mf++){
    int rowa = wm*64 + mf*16 + fm;
    int rowb = wn*64 + mf*16 + fm;
    #pragma unroll
    for (int ks = 0; ks < 2; ks++){
      offA[mf][ks] = rowa*128 + (((unsigned)(ks*4 + kg) ^ (rowa & 7)))*16;
      offB[mf][ks] = rowb*128 + (((unsigned)(ks*4 + kg) ^ (rowb & 7)))*16;
    }
  }

  f32x4 acc[4][4];
  #pragma unroll
  for (int m = 0; m < 4; m++)
    #pragma unroll
    for (int n = 0; n < 4; n++) acc[m][n] = (f32x4){0.f,0.f,0.f,0.f};

  #pragma unroll
  for (int s = 0; s < 12; s++){
    int sec = s >> 2;
    int inner = (s & 3)*64;
    int cbA = (sec == 1 ? 256 : 0) + inner;
    int cbB = (sec == 2 ? 256 : 0) + inner;
    #pragma unroll
    for (int i = 0; i < 4; i++){
      gload16(srcA[i] + cbA, dstA[i]);
      gload16(srcB[i] + cbB, dstB[i]);
    }
    __syncthreads();
    #pragma unroll
    for (int ks = 0; ks < 2; ks++){
      bf16x8 a[4], b[4];
      #pragma unroll
      for (int mf = 0; mf < 4; mf++) a[mf] = *(const bf16x8*)((const char*)sA + offA[mf][ks]);
      #pragma unroll
      for (int nf = 0; nf < 4; nf++) b[nf] = *(const bf16x8*)((const char*)sB + offB[nf][ks]);
      #pragma unroll
      for (int mf = 0; mf < 4; mf++)
        #pragma unroll
        for (int nf = 0; nf < 4; nf++)
          acc[mf][nf] = __builtin_amdgcn_mfma_f32_16x16x32_bf16(a[mf], b[nf], acc[mf][nf], 0, 0, 0);
    }
    __syncthreads();
  }

  #pragma unroll
  for (int mf = 0; mf < 4; mf++){
    int orow = rbl + wm*64 + mf*16 + kg*4;
    #pragma unroll
    for (int nf = 0; nf < 4; nf++){
      int ocol = cb + wn*64 + nf*16 + fm;
      #pragma unroll
      for (int r = 0; r < 4; r++)
        G[(size_t)(orow + r)*NN + ocol] = acc[mf][nf][r];
    }
  }
}

// ---------------- top-K per row from materialized G (named-register list) ----------------
__global__ __launch_bounds__(256)
void k_topk(const float* __restrict__ G, const float* __restrict__ sq,
            int r0, int* __restrict__ idxo){
  __shared__ float lsq[NN];   // 32 KB: sq staged once per block
  int tid = threadIdx.x;
  for (int t = tid; t < NN/4; t += 256)
    ((float4*)lsq)[t] = ((const float4*)sq)[t];
  __syncthreads();

  int wid = tid >> 6, lane = tid & 63;
  int rl = blockIdx.x*4 + wid;
  int gr = r0 + rl;
  const float4* row4 = (const float4*)(G + (size_t)rl*NN);
  const float4* lsq4 = (const float4*)lsq;
  float sqr = lsq[gr];

  float kd0=INFINITY,kd1=INFINITY,kd2=INFINITY,kd3=INFINITY,kd4=INFINITY,
        kd5=INFINITY,kd6=INFINITY,kd7=INFINITY,kd8=INFINITY,kd9=INFINITY,
        kd10=INFINITY,kd11=INFINITY,kd12=INFINITY,kd13=INFINITY,kd14=INFINITY,
        kd15=INFINITY,kd16=INFINITY,kd17=INFINITY,kd18=INFINITY,kd19=INFINITY;
  int ki0=0x7fffffff,ki1=0x7fffffff,ki2=0x7fffffff,ki3=0x7fffffff,ki4=0x7fffffff,
      ki5=0x7fffffff,ki6=0x7fffffff,ki7=0x7fffffff,ki8=0x7fffffff,ki9=0x7fffffff,
      ki10=0x7fffffff,ki11=0x7fffffff,ki12=0x7fffffff,ki13=0x7fffffff,ki14=0x7fffffff,
      ki15=0x7fffffff,ki16=0x7fffffff,ki17=0x7fffffff,ki18=0x7fffffff,ki19=0x7fffffff;

#define ST(U) { bool sw = nk < kd##U; float tv = kd##U; int tq = ki##U; \
      if (sw){ kd##U = nk; ki##U = ni; nk = tv; ni = tq; } }
#define INSE(kc, jc) { if ((kc) < kd19){ float nk = (kc); int ni = (jc); \
      ST(0) ST(1) ST(2) ST(3) ST(4) ST(5) ST(6) ST(7) ST(8) ST(9) \
      ST(10) ST(11) ST(12) ST(13) ST(14) ST(15) ST(16) ST(17) ST(18) ST(19) } }

  float4 gc = row4[lane];
  float4 sc = lsq4[lane];
  #pragma unroll 1
  for (int o = 0; o < 32; o++){
    float4 g = gc, s = sc;
    if (o < 31){
      gc = row4[lane + (o+1)*64];
      sc = lsq4[lane + (o+1)*64];
    }
    int jb = (lane + o*64)*4;
    float k0 = (sqr + s.x) - 2.f*g.x;
    float k1 = (sqr + s.y) - 2.f*g.y;
    float k2 = (sqr + s.z) - 2.f*g.z;
    float k3 = (sqr + s.w) - 2.f*g.w;
    float t19 = kd19;
    float mn = fminf(fminf(k0,k1), fminf(k2,k3));
    if (__any(mn < t19)){
      INSE(k0, jb+0);
      INSE(k1, jb+1);
      INSE(k2, jb+2);
      INSE(k3, jb+3);
    }
  }
#undef INSE
#undef ST

#define MV(A,B) { kd##A = kd##B; ki##A = ki##B; }
  #pragma unroll 1
  for (int r = 0; r < KNN; r++){
    float bv = kd0; int bi = ki0;
    #pragma unroll
    for (int mm = 32; mm; mm >>= 1){
      float ov = __shfl_xor(bv, mm); int oi = __shfl_xor(bi, mm);
      if (ov < bv || (ov == bv && oi < bi)){ bv = ov; bi = oi; }
    }
    if (ki0 == bi){
      MV(0,1) MV(1,2) MV(2,3) MV(3,4) MV(4,5) MV(5,6) MV(6,7) MV(7,8) MV(8,9) MV(9,10)
      MV(10,11) MV(11,12) MV(12,13) MV(13,14) MV(14,15) MV(15,16) MV(16,17) MV(17,18) MV(18,19)
      kd19 = INFINITY; ki19 = 0x7fffffff;
    }
    if (lane == 0) idxo[(size_t)gr*KNN + r] = bi;
  }
#undef MV
}

// ---------------- Wd = Wtop - Wbot ----------------
__global__ void k_wd(const float* __restrict__ W, float* __restrict__ Wd, int rows, int M){
  int t = blockIdx.x*256 + threadIdx.x;
  if (t < rows*M) Wd[t] = W[t] - W[rows*M + t];
}

// ---------------- generic tiled matmul: C = A(nxK) @ B(KxM) [+bias][relu] ----------------
__global__ __launch_bounds__(256)
void k_mm(const float* __restrict__ A, const float* __restrict__ B,
          const float* __restrict__ bias, float* __restrict__ Cout,
          int n, int Kd, int M, int relu){
  __shared__ float la[16][68], lb[16][68];
  int tid = threadIdx.x;
  int rb = blockIdx.y*64, cb = blockIdx.x*64;
  int lr = tid >> 2, lq = (tid & 3)*4;
  int ty = tid >> 4, tx = tid & 15;
  float acc[4][4] = {};
  for (int k0 = 0; k0 < Kd; k0 += 16){
    __syncthreads();
    #pragma unroll
    for (int u = 0; u < 4; u++){
      int k = k0 + lq + u;
      la[lq+u][lr] = (k < Kd) ? A[(size_t)(rb+lr)*Kd + k] : 0.f;
    }
    int kk = tid >> 4; int cc = (tid & 15)*4;
    #pragma unroll
    for (int u = 0; u < 4; u++){
      int c = cb + cc + u; int k = k0 + kk;
      lb[kk][cc+u] = (k < Kd && c < M) ? B[(size_t)k*M + c] : 0.f;
    }
    __syncthreads();
    #pragma unroll
    for (int k = 0; k < 16; k++){
      float4 a = *(const float4*)&la[k][ty*4];
      float4 b = *(const float4*)&lb[k][tx*4];
      float avv[4] = {a.x,a.y,a.z,a.w}, bvv[4] = {b.x,b.y,b.z,b.w};
      #pragma unroll
      for (int u = 0; u < 4; u++)
        #pragma unroll
        for (int v = 0; v < 4; v++) acc[u][v] += avv[u]*bvv[v];
    }
  }
  #pragma unroll
  for (int u = 0; u < 4; u++){
    int r = rb + ty*4 + u;
    #pragma unroll
    for (int v = 0; v < 4; v++){
      int c = cb + tx*4 + v;
      if (c < M){
        float x = acc[u][v] + (bias ? bias[c] : 0.f);
        if (relu) x = fmaxf(x, 0.f);
        Cout[(size_t)r*M + c] = x;
      }
    }
  }
}

// ---------------- stats over A[i]+P[j] per channel ----------------
template<int C>
__global__ __launch_bounds__(256)
void k_stats1(const float* __restrict__ A, const float* __restrict__ P,
              const int* __restrict__ idx, float* __restrict__ ssum, float* __restrict__ ssq){
  __shared__ int si[128], sj[128];
  int tid = threadIdx.x;
  int s0 = blockIdx.x*128;
  if (tid < 128){ si[tid] = (s0 + tid)/KNN; sj[tid] = idx[s0 + tid]; }
  __syncthreads();
  constexpr int MPAR = 256/C;
  int tc = tid % C, sr = tid / C;
  float s = 0.f, q = 0.f;
  for (int m = sr; m < 128; m += MPAR){
    float v = A[(size_t)si[m]*C + tc] + P[(size_t)sj[m]*C + tc];
    s += v; q += v*v;
  }
  if constexpr (MPAR > 1){
    __shared__ float rs[256], rq[256];
    rs[tid] = s; rq[tid] = q; __syncthreads();
    if (sr == 0){
      for (int u = 1; u < MPAR; u++){ s += rs[u*C + tc]; q += rq[u*C + tc]; }
    }
  }
  if (sr == 0){ atomicAdd(&ssum[tc], s); atomicAdd(&ssq[tc], q); }
}

__global__ void k_bn_final(const float* __restrict__ ssum, const float* __restrict__ ssq,
                           const float* __restrict__ g, const float* __restrict__ be,
                           float* __restrict__ sb, float* __restrict__ tb, int C, float invn){
  int c = threadIdx.x;
  if (c < C){
    float mu = ssum[c]*invn;
    float var = fmaxf(ssq[c]*invn - mu*mu, 0.f);
    float s = g[c]*rsqrtf(var + 1e-5f);
    sb[c] = s; tb[c] = be[c] - mu*s;
  }
}

// ---------------- MFMA per-edge matmul (C=256) + fused column stats ----------------
// out = relu(bn1(A[i]+P[j])) @ W + bias; split-bf16: Ehi@Whi + Elo@Whi + Ehi@Wlo.
// Block = 64 edges x 256 cols; prep batched 8-deep (R11 post-mortem: unroll-1
// serialized the gathers). Fused stats: per-channel sum/sumsq of out values
// (atomicAdd; replaces the 168 MB colstats pass).
__global__ __launch_bounds__(256, 2)
void k_edge_mfma(const float* __restrict__ A, const float* __restrict__ P,
                 const int* __restrict__ idx, const float* __restrict__ sb,
                 const float* __restrict__ tb, const unsigned short* __restrict__ Wthi,
                 const unsigned short* __restrict__ Wtlo, const float* __restrict__ bias,
                 float* __restrict__ out, float* __restrict__ ssum, float* __restrict__ ssq){
  __shared__ unsigned short ehi[64*256];   // 32 KB
  __shared__ unsigned short elo[64*256];   // 32 KB
  __shared__ int sj[64];
  int tid = threadIdx.x;
  int lw = tid >> 6, l = tid & 63;
  int s0 = blockIdx.x*64;
  if (tid < 64) sj[tid] = idx[s0 + tid];
  float sbc = sb[tid], tbc = tb[tid];
  __syncthreads();

  // prep: batched loads, 16 in flight per group
  #pragma unroll 1
  for (int g = 0; g < 8; g++){
    float va[8];
    #pragma unroll
    for (int u = 0; u < 8; u++){
      int it = g*8 + u;
      int i = (s0 + it)/KNN;
      int j = sj[it];
      va[u] = A[(size_t)i*256 + tid] + P[(size_t)j*256 + tid];
    }
    #pragma unroll
    for (int u = 0; u < 8; u++){
      int it = g*8 + u;
      float v = fmaxf(va[u]*sbc + tbc, 0.f);
      unsigned short h = f2bf(v);
      unsigned short lo = f2bf(v - bf2f(h));
      unsigned off = (unsigned)it*512 + (((unsigned)tid*2) ^ (((unsigned)it & 7) << 4));
      *(unsigned short*)((char*)ehi + off) = h;
      *(unsigned short*)((char*)elo + off) = lo;
    }
  }
  __syncthreads();

  int fm = l & 15, kg = l >> 4;
  const unsigned short* bhi[4];
  const unsigned short* blo[4];
  float bz[4];
  #pragma unroll
  for (int nf = 0; nf < 4; nf++){
    int col = lw*64 + nf*16 + fm;
    bhi[nf] = Wthi + (size_t)col*256 + kg*8;
    blo[nf] = Wtlo + (size_t)col*256 + kg*8;
    bz[nf] = bias[col];
  }

  f32x4 acc[4][4];
  #pragma unroll
  for (int m = 0; m < 4; m++)
    #pragma unroll
    for (int n = 0; n < 4; n++) acc[m][n] = (f32x4){0.f,0.f,0.f,0.f};

  #pragma unroll 1
  for (int sec = 0; sec < 3; sec++){
    const char* abase = (sec == 1) ? (const char*)elo : (const char*)ehi;
    int bsec = (sec == 2);
    #pragma unroll 1
    for (int st = 0; st < 8; st++){
      int g = st*4 + kg;
      bf16x8 a[4], b[4];
      #pragma unroll
      for (int mf = 0; mf < 4; mf++){
        int row = mf*16 + fm;
        a[mf] = *(const bf16x8*)(abase + row*512 + ((unsigned)(g ^ (row & 7)))*16);
      }
      #pragma unroll
      for (int nf = 0; nf < 4; nf++){
        const unsigned short* bp = bsec ? blo[nf] : bhi[nf];
        b[nf] = *(const bf16x8*)(bp + st*32);
      }
      #pragma unroll
      for (int mf = 0; mf < 4; mf++)
        #pragma unroll
        for (int nf = 0; nf < 4; nf++)
          acc[mf][nf] = __builtin_amdgcn_mfma_f32_16x16x32_bf16(a[mf], b[nf], acc[mf][nf], 0, 0, 0);
    }
  }

  // write + fused stats. C/D: col = lane&15, row = (lane>>4)*4 + r
  float s4[4], q4[4];
  #pragma unroll
  for (int nf = 0; nf < 4; nf++){ s4[nf] = 0.f; q4[nf] = 0.f; }
  #pragma unroll
  for (int mf = 0; mf < 4; mf++){
    #pragma unroll
    for (int nf = 0; nf < 4; nf++){
      int col = lw*64 + nf*16 + fm;
      #pragma unroll
      for (int r = 0; r < 4; r++){
        int row = s0 + mf*16 + kg*4 + r;
        float v = acc[mf][nf][r] + bz[nf];
        out[(size_t)row*256 + col] = v;
        s4[nf] += v; q4[nf] += v*v;
      }
    }
  }
  #pragma unroll
  for (int nf = 0; nf < 4; nf++){
    s4[nf] += __shfl_xor(s4[nf], 16); q4[nf] += __shfl_xor(q4[nf], 16);
    s4[nf] += __shfl_xor(s4[nf], 32); q4[nf] += __shfl_xor(q4[nf], 32);
  }
  if (kg == 0){
    #pragma unroll
    for (int nf = 0; nf < 4; nf++){
      int col = lw*64 + nf*16 + fm;
      atomicAdd(&ssum[col], s4[nf]);
      atomicAdd(&ssq[col], q4[nf]);
    }
  }
}

// ---------------- MFMA per-edge matmul (C=64, K=64) + fused column stats ----------------
// Block = 128 edges x 64 cols; 4 waves = 2(m) x 2(n); wave = 64 edges x 32 cols.
__global__ __launch_bounds__(256, 2)
void k_edge_mfma64(const float* __restrict__ A, const float* __restrict__ P,
                   const int* __restrict__ idx, const float* __restrict__ sb,
                   const float* __restrict__ tb, const unsigned short* __restrict__ Wthi,
                   const unsigned short* __restrict__ Wtlo, const float* __restrict__ bias,
                   float* __restrict__ out, float* __restrict__ ssum, float* __restrict__ ssq){
  __shared__ unsigned short ehi[128*64];   // 16 KB
  __shared__ unsigned short elo[128*64];   // 16 KB
  __shared__ int sj[128];
  int tid = threadIdx.x;
  int lw = tid >> 6, l = tid & 63;
  int s0 = blockIdx.x*128;
  if (tid < 128) sj[tid] = idx[s0 + tid];
  int col0 = tid & 63, rgrp = tid >> 6;
  float sbc = sb[col0], tbc = tb[col0];
  __syncthreads();

  // prep: thread covers rows {rgrp, rgrp+4, ...} at col col0, batched 8-deep
  #pragma unroll 1
  for (int g = 0; g < 4; g++){
    float va[8];
    #pragma unroll
    for (int u = 0; u < 8; u++){
      int it = (g*8 + u)*4 + rgrp;
      int i = (s0 + it)/KNN;
      int j = sj[it];
      va[u] = A[(size_t)i*64 + col0] + P[(size_t)j*64 + col0];
    }
    #pragma unroll
    for (int u = 0; u < 8; u++){
      int it = (g*8 + u)*4 + rgrp;
      float v = fmaxf(va[u]*sbc + tbc, 0.f);
      unsigned short h = f2bf(v);
      unsigned short lo = f2bf(v - bf2f(h));
      unsigned off = (unsigned)it*128 + (((unsigned)col0*2) ^ (((unsigned)it & 7) << 4));
      *(unsigned short*)((char*)ehi + off) = h;
      *(unsigned short*)((char*)elo + off) = lo;
    }
  }
  __syncthreads();

  int wm = lw >> 1, wn = lw & 1;
  int fm = l & 15, kg = l >> 4;
  const unsigned short* bhi[2];
  const unsigned short* blo[2];
  float bz[2];
  #pragma unroll
  for (int nf = 0; nf < 2; nf++){
    int col = wn*32 + nf*16 + fm;
    bhi[nf] = Wthi + (size_t)col*64 + kg*8;
    blo[nf] = Wtlo + (size_t)col*64 + kg*8;
    bz[nf] = bias[col];
  }

  f32x4 acc[4][2];
  #pragma unroll
  for (int m = 0; m < 4; m++)
    #pragma unroll
    for (int n = 0; n < 2; n++) acc[m][n] = (f32x4){0.f,0.f,0.f,0.f};

  #pragma unroll 1
  for (int sec = 0; sec < 3; sec++){
    const char* abase = (sec == 1) ? (const char*)elo : (const char*)ehi;
    int bsec = (sec == 2);
    #pragma unroll
    for (int ks = 0; ks < 2; ks++){
      int g = ks*4 + kg;
      bf16x8 a[4], b[2];
      #pragma unroll
      for (int mf = 0; mf < 4; mf++){
        int row = wm*64 + mf*16 + fm;
        a[mf] = *(const bf16x8*)(abase + row*128 + ((unsigned)(g ^ (row & 7)))*16);
      }
      #pragma unroll
      for (int nf = 0; nf < 2; nf++){
        const unsigned short* bp = bsec ? blo[nf] : bhi[nf];
        b[nf] = *(const bf16x8*)(bp + ks*32);
      }
      #pragma unroll
      for (int mf = 0; mf < 4; mf++)
        #pragma unroll
        for (int nf = 0; nf < 2; nf++)
          acc[mf][nf] = __builtin_amdgcn_mfma_f32_16x16x32_bf16(a[mf], b[nf], acc[mf][nf], 0, 0, 0);
    }
  }

  float s2[2], q2[2];
  #pragma unroll
  for (int nf = 0; nf < 2; nf++){ s2[nf] = 0.f; q2[nf] = 0.f; }
  #pragma unroll
  for (int mf = 0; mf < 4; mf++){
    #pragma unroll
    for (int nf = 0; nf < 2; nf++){
      int col = wn*32 + nf*16 + fm;
      #pragma unroll
      for (int r = 0; r < 4; r++){
        int row = s0 + wm*64 + mf*16 + kg*4 + r;
        float v = acc[mf][nf][r] + bz[nf];
        out[(size_t)row*64 + col] = v;
        s2[nf] += v; q2[nf] += v*v;
      }
    }
  }
  #pragma unroll
  for (int nf = 0; nf < 2; nf++){
    s2[nf] += __shfl_xor(s2[nf], 16); q2[nf] += __shfl_xor(q2[nf], 16);
    s2[nf] += __shfl_xor(s2[nf], 32); q2[nf] += __shfl_xor(q2[nf], 32);
  }
  if (kg == 0){
    #pragma unroll
    for (int nf = 0; nf < 2; nf++){
      int col = wn*32 + nf*16 + fm;
      atomicAdd(&ssum[col], s2[nf]);
      atomicAdd(&ssq[col], q2[nf]);
    }
  }
}

// ---------------- bn2 + relu + max over K ----------------
template<int C>
__global__ void k_maxpool(const float* __restrict__ X, const float* __restrict__ sb,
                          const float* __restrict__ tb, float* __restrict__ H){
  constexpr int NPB = 256/C;
  int node = blockIdx.x*NPB + threadIdx.x / C;
  int c = threadIdx.x % C;
  float s = sb[c], t = tb[c];
  float mx = 0.f;
  for (int k = 0; k < KNN; k++){
    float v = X[(size_t)(node*KNN + k)*C + c]*s + t;
    mx = fmaxf(mx, v);
  }
  H[(size_t)node*C + c] = mx;
}

// ---------------- gconv aggregation ----------------
template<int C>
__global__ void k_agg(const float* __restrict__ X, const int* __restrict__ roff,
                      const int* __restrict__ csr, const float* __restrict__ dout,
                      const float* __restrict__ din, float* __restrict__ XA){
  int i = blockIdx.x; int c = threadIdx.x;
  float acc = 0.f;
  int b = roff[i], e = roff[i+1];
  for (int t = b; t < e; t++){
    int s = csr[t];
    acc += X[(size_t)s*C + c]*dout[s];
  }
  XA[(size_t)i*C + c] = acc*din[i];
}

// ================= host =================
extern "C" void kernel_launch(void* const* d_in, const int* in_sizes, int n_in,
                              void* d_out, int out_size, void* d_ws, size_t ws_size,
                              hipStream_t stream){
  const float* feat = (const float*)d_in[0];
  const int*   src  = (const int*)d_in[1];
  const int*   dst  = (const int*)d_in[2];
  const float* Wc1  = (const float*)d_in[3];
  const float* bc1  = (const float*)d_in[4];
  const float* Wc2  = (const float*)d_in[5];
  const float* bc2  = (const float*)d_in[6];
  const float* Wc3  = (const float*)d_in[7];
  const float* bc3  = (const float*)d_in[8];
  const float* W11  = (const float*)d_in[9];
  const float* b11  = (const float*)d_in[10];
  const float* g11  = (const float*)d_in[11];
  const float* be11 = (const float*)d_in[12];
  const float* W12  = (const float*)d_in[13];
  const float* b12  = (const float*)d_in[14];
  const float* g12  = (const float*)d_in[15];
  const float* be12 = (const float*)d_in[16];
  const float* W21  = (const float*)d_in[17];
  const float* b21  = (const float*)d_in[18];
  const float* g21  = (const float*)d_in[19];
  const float* be21 = (const float*)d_in[20];
  const float* W22  = (const float*)d_in[21];
  const float* b22  = (const float*)d_in[22];
  const float* g22  = (const float*)d_in[23];
  const float* be22 = (const float*)d_in[24];
  float* out = (float*)d_out;

  char* w = (char*)d_ws; size_t off = 0;
  auto alloc = [&](size_t bytes)->void*{
    void* p = w + off;
    off += bytes; off = (off + 255) & ~(size_t)255;
    return p;
  };
  int* cnt_s  = (int*)alloc(NN*4);
  int* cnt_d  = (int*)alloc(NN*4);
  int* roff   = (int*)alloc((NN+1)*4);
  int* cursor = (int*)alloc(NN*4);
  int* csr    = (int*)alloc(NE*4);
  int* idx    = (int*)alloc((size_t)NN*KNN*4);
  float* dout = (float*)alloc(NN*4);
  float* din  = (float*)alloc(NN*4);
  float* sqv  = (float*)alloc(NN*4);
  float* h1   = (float*)alloc((size_t)NN*256*4);
  float* h2   = (float*)alloc((size_t)NN*256*4);
  float* h3   = (float*)alloc((size_t)NN*256*4);
  float* h4   = (float*)alloc((size_t)NN*64*4);
  float* xa   = (float*)alloc((size_t)NN*256*4);
  float* Abuf = (float*)alloc((size_t)NN*256*4);
  float* Pbuf = (float*)alloc((size_t)NN*256*4);
  float* Wd   = (float*)alloc(256*256*4);
  float* ssum = (float*)alloc(256*4);
  float* ssq  = (float*)alloc(256*4);
  float* sbn  = (float*)alloc(256*4);
  float* tbn  = (float*)alloc(256*4);
  unsigned short* wthi = (unsigned short*)alloc(256*256*2);
  unsigned short* wtlo = (unsigned short*)alloc(256*256*2);
  unsigned short* w64hi = (unsigned short*)alloc(64*64*2);
  unsigned short* w64lo = (unsigned short*)alloc(64*64*2);
  float* out2 = (float*)alloc((size_t)NN*KNN*256*4);   // 167.8 MB
  // kNN scratch aliases out2 (consumed before edge kernels write out2):
  float* gram = out2;                                        // CH*NN*4 = 134.2 MB
  unsigned short* xcat = (unsigned short*)(out2 + (size_t)CH*NN);  // 8.4 MB
  (void)ws_size; (void)n_in; (void)in_sizes; (void)out_size;

  const float invn = 1.0f / (float)(NN*KNN);

  // graph prep
  k_zero_i<<<32, 256, 0, stream>>>(cnt_s, NN);
  k_zero_i<<<32, 256, 0, stream>>>(cnt_d, NN);
  k_zero_i<<<32, 256, 0, stream>>>(cursor, NN);
  k_count<<<NE/256, 256, 0, stream>>>(src, dst, cnt_s, cnt_d);
  k_deg<<<32, 256, 0, stream>>>(cnt_s, cnt_d, dout, din);
  k_scan<<<1, 256, 0, stream>>>(cnt_d, roff);
  k_fill<<<NE/256, 256, 0, stream>>>(src, dst, roff, cursor, csr);

  // gconv1 -> h1
  k_gconv1<<<NN/4, 256, 0, stream>>>(feat, roff, csr, dout, din, Wc1, bc1, h1);

  // ---- edge conv 1 (input h1, 256 -> 256 -> 256) ----
  k_sq<<<NN/4, 256, 0, stream>>>(h1, sqv);
  k_split<<<NN, 256, 0, stream>>>(h1, xcat);
  for (int r0 = 0; r0 < NN; r0 += CH){
    k_gram_mfma<<<dim3(NN/GBN, CH/GBM), 256, 0, stream>>>(xcat, gram, r0);
    k_topk<<<CH/4, 256, 0, stream>>>(gram, sqv, r0, idx);
  }
  k_wd<<<256, 256, 0, stream>>>(W11, Wd, 256, 256);
  k_wsplit<<<256, 256, 0, stream>>>(W12, wthi, wtlo);
  k_mm<<<dim3(4, NN/64), 256, 0, stream>>>(h1, Wd, b11, Abuf, NN, 256, 256, 0);
  k_mm<<<dim3(4, NN/64), 256, 0, stream>>>(h1, W11 + 256*256, nullptr, Pbuf, NN, 256, 256, 0);
  k_zero<<<2, 256, 0, stream>>>(ssum, 256); k_zero<<<2, 256, 0, stream>>>(ssq, 256);
  k_stats1<256><<<NN*KNN/128, 256, 0, stream>>>(Abuf, Pbuf, idx, ssum, ssq);
  k_bn_final<<<1, 256, 0, stream>>>(ssum, ssq, g11, be11, sbn, tbn, 256, invn);
  k_zero<<<2, 256, 0, stream>>>(ssum, 256); k_zero<<<2, 256, 0, stream>>>(ssq, 256);
  k_edge_mfma<<<NN*KNN/64, 256, 0, stream>>>(Abuf, Pbuf, idx, sbn, tbn, wthi, wtlo, b12, out2, ssum, ssq);
  k_bn_final<<<1, 256, 0, stream>>>(ssum, ssq, g12, be12, sbn, tbn, 256, invn);
  k_maxpool<256><<<NN, 256, 0, stream>>>(out2, sbn, tbn, h2);

  // gconv2 -> h3
  k_agg<256><<<NN, 256, 0, stream>>>(h2, roff, csr, dout, din, xa);
  k_mm<<<dim3(4, NN/64), 256, 0, stream>>>(xa, Wc2, bc2, h3, NN, 256, 256, 1);

  // ---- edge conv 2 (input h3, 256 -> 64 -> 64) ----
  k_sq<<<NN/4, 256, 0, stream>>>(h3, sqv);
  k_split<<<NN, 256, 0, stream>>>(h3, xcat);
  for (int r0 = 0; r0 < NN; r0 += CH){
    k_gram_mfma<<<dim3(NN/GBN, CH/GBM), 256, 0, stream>>>(xcat, gram, r0);
    k_topk<<<CH/4, 256, 0, stream>>>(gram, sqv, r0, idx);
  }
  k_wd<<<64, 256, 0, stream>>>(W21, Wd, 256, 64);
  k_wsplit64<<<64, 64, 0, stream>>>(W22, w64hi, w64lo);
  k_mm<<<dim3(1, NN/64), 256, 0, stream>>>(h3, Wd, b21, Abuf, NN, 256, 64, 0);
  k_mm<<<dim3(1, NN/64), 256, 0, stream>>>(h3, W21 + 256*64, nullptr, Pbuf, NN, 256, 64, 0);
  k_zero<<<2, 256, 0, stream>>>(ssum, 256); k_zero<<<2, 256, 0, stream>>>(ssq, 256);
  k_stats1<64><<<NN*KNN/128, 256, 0, stream>>>(Abuf, Pbuf, idx, ssum, ssq);
  k_bn_final<<<1, 256, 0, stream>>>(ssum, ssq, g21, be21, sbn, tbn, 64, invn);
  k_zero<<<2, 256, 0, stream>>>(ssum, 256); k_zero<<<2, 256, 0, stream>>>(ssq, 256);
  k_edge_mfma64<<<NN*KNN/128, 256, 0, stream>>>(Abuf, Pbuf, idx, sbn, tbn, w64hi, w64lo, b22, out2, ssum, ssq);
  k_bn_final<<<1, 256, 0, stream>>>(ssum, ssq, g22, be22, sbn, tbn, 64, invn);
  k_maxpool<64><<<NN/4, 256, 0, stream>>>(out2, sbn, tbn, h4);

  // gconv3 -> out
  k_agg<64><<<NN, 64, 0, stream>>>(h4, roff, csr, dout, din, xa);
  k_mm<<<dim3(1, NN/64), 256, 0, stream>>>(xa, Wc3, bc3, out, NN, 64, 32, 0);
}